// Round 1
// baseline (1211.875 us; speedup 1.0000x reference)
//
#include <hip/hip_runtime.h>

#define NN 100000
#define NE 1600000
#define SCAN_CH 1024

// ---------------- CSR build (dst-sorted edge lists) ----------------

__global__ __launch_bounds__(256) void k_hist(const int* __restrict__ dst,
                                              int* __restrict__ counts) {
    int e = blockIdx.x * 256 + threadIdx.x;
    if (e < NE) atomicAdd(&counts[dst[e]], 1);
}

__global__ __launch_bounds__(256) void k_scan1(const int* __restrict__ counts,
                                               int* __restrict__ csum) {
    __shared__ int sd[256];
    int t = threadIdx.x;
    int base = blockIdx.x * SCAN_CH + t * 4;
    int s = 0;
#pragma unroll
    for (int u = 0; u < 4; ++u) {
        int i = base + u;
        if (i < NN) s += counts[i];
    }
    sd[t] = s;
    __syncthreads();
    for (int off = 128; off > 0; off >>= 1) {
        if (t < off) sd[t] += sd[t + off];
        __syncthreads();
    }
    if (t == 0) csum[blockIdx.x] = sd[0];
}

__global__ __launch_bounds__(64) void k_scan2(int* csum, int nch) {
    if (threadIdx.x == 0 && blockIdx.x == 0) {
        int run = 0;
        for (int i = 0; i < nch; ++i) {
            int v = csum[i];
            csum[i] = run;
            run += v;
        }
    }
}

__global__ __launch_bounds__(256) void k_scan3(const int* __restrict__ counts,
                                               const int* __restrict__ csum,
                                               int* __restrict__ row_ptr) {
    __shared__ int sd[256];
    int t = threadIdx.x, b = blockIdx.x;
    int base = b * SCAN_CH + t * 4;
    int v[4];
    int s = 0;
#pragma unroll
    for (int u = 0; u < 4; ++u) {
        int i = base + u;
        v[u] = (i < NN) ? counts[i] : 0;
        s += v[u];
    }
    sd[t] = s;
    __syncthreads();
    // Hillis-Steele inclusive scan over the 256 thread sums
    for (int off = 1; off < 256; off <<= 1) {
        int x = (t >= off) ? sd[t - off] : 0;
        __syncthreads();
        sd[t] += x;
        __syncthreads();
    }
    int excl = (t == 0) ? 0 : sd[t - 1];
    int run = csum[b] + excl;
#pragma unroll
    for (int u = 0; u < 4; ++u) {
        int i = base + u;
        if (i < NN) row_ptr[i] = run;
        run += v[u];
    }
    if (b == 0 && t == 0) row_ptr[NN] = NE;
}

__global__ __launch_bounds__(256) void k_copy(const int* __restrict__ a,
                                              int* __restrict__ b) {
    int i = blockIdx.x * 256 + threadIdx.x;
    if (i < NN) b[i] = a[i];
}

__global__ __launch_bounds__(256) void k_scatter(const int* __restrict__ src,
                                                 const int* __restrict__ dst,
                                                 int* __restrict__ nxt,
                                                 int* __restrict__ src_sorted) {
    int e = blockIdx.x * 256 + threadIdx.x;
    if (e < NE) {
        int d = dst[e];
        int p = atomicAdd(&nxt[d], 1);
        src_sorted[p] = src[e];
    }
}

// ---------------- GEMM + attention-logit epilogue ----------------
// h[n][128] = x[n][:] @ W ; a_src[n][q] = dot(h[n][32q:32q+32], att_src[q]),
// same for a_dst. Block: 64 nodes, 256 threads; thread (nl, q) computes the
// full head-q (32 channels) output of node nl. W read via all-lane-uniform
// float4 loads (L1/L2 resident, 64 KB).
__global__ __launch_bounds__(256) void k_gemm(
    const float* __restrict__ x, int xrs, int xcs,
    const float* __restrict__ W,
    const float* __restrict__ atts, const float* __restrict__ attd,
    float* __restrict__ h, float* __restrict__ a_src, float* __restrict__ a_dst) {
    __shared__ float xs[64][129];  // +1 pad: bank = (node + k) % 32 -> 2-way (free)
    const int t = threadIdx.x;
    const int row0 = blockIdx.x * 64;
    if (xcs == 1) {
#pragma unroll
        for (int i = 0; i < 8; ++i) {
            int f4 = t + 256 * i;
            int r = f4 >> 5, c4 = f4 & 31;
            int node = row0 + r;
            float4 v = make_float4(0.f, 0.f, 0.f, 0.f);
            if (node < NN) v = *(const float4*)(x + (size_t)node * xrs + c4 * 4);
            xs[r][c4 * 4 + 0] = v.x;
            xs[r][c4 * 4 + 1] = v.y;
            xs[r][c4 * 4 + 2] = v.z;
            xs[r][c4 * 4 + 3] = v.w;
        }
    } else {
#pragma unroll
        for (int i = 0; i < 8; ++i) {
            int f4 = t + 256 * i;
            int r = f4 >> 5, c4 = f4 & 31;
            int node = row0 + r;
#pragma unroll
            for (int u = 0; u < 4; ++u) {
                float v = 0.f;
                if (node < NN) v = x[(size_t)node * xrs + (size_t)(c4 * 4 + u) * xcs];
                xs[r][c4 * 4 + u] = v;
            }
        }
    }
    __syncthreads();
    const int nl = t & 63, q = t >> 6;
    float acc[32];
#pragma unroll
    for (int j = 0; j < 32; ++j) acc[j] = 0.f;
    const float* wq = W + q * 32;
#pragma unroll 2
    for (int k = 0; k < 128; ++k) {
        float xv = xs[nl][k];
        const float4* w4 = (const float4*)(wq + (size_t)k * 128);
#pragma unroll
        for (int j4 = 0; j4 < 8; ++j4) {
            float4 wv = w4[j4];
            acc[j4 * 4 + 0] = fmaf(xv, wv.x, acc[j4 * 4 + 0]);
            acc[j4 * 4 + 1] = fmaf(xv, wv.y, acc[j4 * 4 + 1]);
            acc[j4 * 4 + 2] = fmaf(xv, wv.z, acc[j4 * 4 + 2]);
            acc[j4 * 4 + 3] = fmaf(xv, wv.w, acc[j4 * 4 + 3]);
        }
    }
    int node = row0 + nl;
    if (node < NN) {
        float as = 0.f, ad = 0.f;
#pragma unroll
        for (int j4 = 0; j4 < 8; ++j4) {
            float4 sv = *(const float4*)(atts + q * 32 + j4 * 4);
            float4 dv = *(const float4*)(attd + q * 32 + j4 * 4);
            as += acc[j4 * 4 + 0] * sv.x + acc[j4 * 4 + 1] * sv.y +
                  acc[j4 * 4 + 2] * sv.z + acc[j4 * 4 + 3] * sv.w;
            ad += acc[j4 * 4 + 0] * dv.x + acc[j4 * 4 + 1] * dv.y +
                  acc[j4 * 4 + 2] * dv.z + acc[j4 * 4 + 3] * dv.w;
            float4 hv = make_float4(acc[j4 * 4 + 0], acc[j4 * 4 + 1],
                                    acc[j4 * 4 + 2], acc[j4 * 4 + 3]);
            *(float4*)(h + (size_t)node * 128 + q * 32 + j4 * 4) = hv;
        }
        a_src[node * 4 + q] = as;
        a_dst[node * 4 + q] = ad;
    }
}

// ---------------- per-node aggregation (one wave per node) ----------------
// lane l owns channels {2l, 2l+1}; head = l>>4. Pass 1: register segment-max.
// Pass 2: den += exp(e-m); num += exp(e-m) * h[src] (float2 coalesced gather).
// Epilogue: out = relu(num/den + bias), written to stride-2 slot of d_out.
__global__ __launch_bounds__(256) void k_agg(
    const float* __restrict__ h,
    const float* __restrict__ a_src, const float* __restrict__ a_dst,
    const int* __restrict__ row_ptr, const int* __restrict__ src_sorted,
    const float* __restrict__ bias,
    float* __restrict__ out, int ors, int ocs) {
    const int lane = threadIdx.x & 63;
    const int node = blockIdx.x * 4 + (threadIdx.x >> 6);
    if (node >= NN) return;
    const int head = lane >> 4;
    const int e0 = row_ptr[node], e1 = row_ptr[node + 1];
    const float adv = a_dst[node * 4 + head];
    float m = -1e30f;
    for (int e = e0; e < e1; ++e) {
        int s = src_sorted[e];
        float v = a_src[s * 4 + head] + adv;
        v = v > 0.f ? v : 0.2f * v;
        m = fmaxf(m, v);
    }
    float den = 0.f, acc0 = 0.f, acc1 = 0.f;
    const float2* __restrict__ h2 = (const float2*)h;
    for (int e = e0; e < e1; ++e) {
        int s = src_sorted[e];
        float v = a_src[s * 4 + head] + adv;
        v = v > 0.f ? v : 0.2f * v;
        float ex = __expf(v - m);
        den += ex;
        float2 hv = h2[(size_t)s * 64 + lane];
        acc0 = fmaf(ex, hv.x, acc0);
        acc1 = fmaf(ex, hv.y, acc1);
    }
    float inv = den > 0.f ? 1.0f / den : 0.f;
    int c0 = lane * 2;
    float r0 = fmaxf(fmaf(acc0, inv, bias[c0]), 0.f);
    float r1 = fmaxf(fmaf(acc1, inv, bias[c0 + 1]), 0.f);
    out[(size_t)node * ors + (size_t)c0 * ocs] = r0;
    out[(size_t)node * ors + (size_t)(c0 + 1) * ocs] = r1;
}

// ---------------- launch ----------------

extern "C" void kernel_launch(void* const* d_in, const int* in_sizes, int n_in,
                              void* d_out, int out_size, void* d_ws, size_t ws_size,
                              hipStream_t stream) {
    const float* x   = (const float*)d_in[0];
    const int*   ei  = (const int*)d_in[1];
    const float* W1  = (const float*)d_in[2];
    const float* as1 = (const float*)d_in[3];
    const float* ad1 = (const float*)d_in[4];
    const float* b1  = (const float*)d_in[5];
    const float* W2  = (const float*)d_in[6];
    const float* as2 = (const float*)d_in[7];
    const float* ad2 = (const float*)d_in[8];
    const float* b2  = (const float*)d_in[9];
    float* out = (float*)d_out;
    const int* src = ei;
    const int* dst = ei + NE;

    // workspace layout (~62 MB)
    char* w = (char*)d_ws;
    size_t off = 0;
    auto alloc = [&](size_t bytes) -> void* {
        void* p = w + off;
        off = (off + bytes + 255) & ~((size_t)255);
        return p;
    };
    float* h        = (float*)alloc((size_t)NN * 128 * 4);
    float* a_src    = (float*)alloc((size_t)NN * 4 * 4);
    float* a_dst    = (float*)alloc((size_t)NN * 4 * 4);
    int* counts     = (int*)alloc((size_t)NN * 4);
    int* row_ptr    = (int*)alloc((size_t)(NN + 1) * 4);
    int* nxt        = (int*)alloc((size_t)NN * 4);
    int* csum       = (int*)alloc(4096);
    int* src_sorted = (int*)alloc((size_t)NE * 4);

    const int nch = (NN + SCAN_CH - 1) / SCAN_CH;  // 98

    // CSR build (once; shared by both layers)
    hipMemsetAsync(counts, 0, (size_t)NN * 4, stream);
    k_hist<<<(NE + 255) / 256, 256, 0, stream>>>(dst, counts);
    k_scan1<<<nch, 256, 0, stream>>>(counts, csum);
    k_scan2<<<1, 64, 0, stream>>>(csum, nch);
    k_scan3<<<nch, 256, 0, stream>>>(counts, csum, row_ptr);
    k_copy<<<(NN + 255) / 256, 256, 0, stream>>>(row_ptr, nxt);
    k_scatter<<<(NE + 255) / 256, 256, 0, stream>>>(src, dst, nxt, src_sorted);

    const int gemm_grid = (NN + 63) / 64;
    const int agg_grid = (NN + 3) / 4;

    // layer 1: x (contiguous) -> h, logits; aggregate -> x1 in d_out slot k=0
    k_gemm<<<gemm_grid, 256, 0, stream>>>(x, 128, 1, W1, as1, ad1, h, a_src, a_dst);
    k_agg<<<agg_grid, 256, 0, stream>>>(h, a_src, a_dst, row_ptr, src_sorted, b1,
                                        out + 0, 256, 2);
    // layer 2: x1 read strided from d_out -> h, logits; aggregate -> slot k=1
    k_gemm<<<gemm_grid, 256, 0, stream>>>(out, 256, 2, W2, as2, ad2, h, a_src, a_dst);
    k_agg<<<agg_grid, 256, 0, stream>>>(h, a_src, a_dst, row_ptr, src_sorted, b2,
                                        out + 1, 256, 2);
}

// Round 2
// 815.707 us; speedup vs baseline: 1.4857x; 1.4857x over previous
//
#include <hip/hip_runtime.h>

#define NN 100000
#define NE 1600000
#define SCAN_CH 1024

// ---------------- CSR build (dst-sorted edge lists) ----------------

__global__ __launch_bounds__(256) void k_hist(const int* __restrict__ dst,
                                              int* __restrict__ counts) {
    int e = blockIdx.x * 256 + threadIdx.x;
    if (e < NE) atomicAdd(&counts[dst[e]], 1);
}

__global__ __launch_bounds__(256) void k_scan1(const int* __restrict__ counts,
                                               int* __restrict__ csum) {
    __shared__ int sd[256];
    int t = threadIdx.x;
    int base = blockIdx.x * SCAN_CH + t * 4;
    int s = 0;
#pragma unroll
    for (int u = 0; u < 4; ++u) {
        int i = base + u;
        if (i < NN) s += counts[i];
    }
    sd[t] = s;
    __syncthreads();
    for (int off = 128; off > 0; off >>= 1) {
        if (t < off) sd[t] += sd[t + off];
        __syncthreads();
    }
    if (t == 0) csum[blockIdx.x] = sd[0];
}

__global__ __launch_bounds__(64) void k_scan2(int* csum, int nch) {
    if (threadIdx.x == 0 && blockIdx.x == 0) {
        int run = 0;
        for (int i = 0; i < nch; ++i) {
            int v = csum[i];
            csum[i] = run;
            run += v;
        }
    }
}

__global__ __launch_bounds__(256) void k_scan3(const int* __restrict__ counts,
                                               const int* __restrict__ csum,
                                               int* __restrict__ row_ptr,
                                               int* __restrict__ nxt) {
    __shared__ int sd[256];
    int t = threadIdx.x, b = blockIdx.x;
    int base = b * SCAN_CH + t * 4;
    int v[4];
    int s = 0;
#pragma unroll
    for (int u = 0; u < 4; ++u) {
        int i = base + u;
        v[u] = (i < NN) ? counts[i] : 0;
        s += v[u];
    }
    sd[t] = s;
    __syncthreads();
    for (int off = 1; off < 256; off <<= 1) {
        int x = (t >= off) ? sd[t - off] : 0;
        __syncthreads();
        sd[t] += x;
        __syncthreads();
    }
    int excl = (t == 0) ? 0 : sd[t - 1];
    int run = csum[b] + excl;
#pragma unroll
    for (int u = 0; u < 4; ++u) {
        int i = base + u;
        if (i < NN) {
            row_ptr[i] = run;
            nxt[i] = run;
        }
        run += v[u];
    }
    if (b == 0 && t == 0) row_ptr[NN] = NE;
}

__global__ __launch_bounds__(256) void k_scatter(const int* __restrict__ src,
                                                 const int* __restrict__ dst,
                                                 int* __restrict__ nxt,
                                                 int* __restrict__ src_sorted) {
    int e = blockIdx.x * 256 + threadIdx.x;
    if (e < NE) {
        int d = dst[e];
        int p = atomicAdd(&nxt[d], 1);
        src_sorted[p] = src[e];
    }
}

// ---------------- GEMM + attention-logit epilogue ----------------
// 128 nodes per 256-thread block; thread (nl, q) computes head-q (32 ch) for
// nodes {row0+nl, row0+64+nl}. W addresses are wave-uniform (q = t>>6) ->
// scalarizable; 64 FMA per 2 LDS reads + 8 W loads.
__global__ __launch_bounds__(256) void k_gemm(
    const float* __restrict__ x, int strided2,
    const float* __restrict__ W,
    const float* __restrict__ atts, const float* __restrict__ attd,
    float* __restrict__ h, float* __restrict__ a_src, float* __restrict__ a_dst) {
    __shared__ float xs[128][129];  // bank = (nl + k) % 32 -> 2-way (free)
    const int t = threadIdx.x;
    const int row0 = blockIdx.x * 128;
    if (!strided2) {
#pragma unroll
        for (int i = 0; i < 16; ++i) {
            int f4 = t + 256 * i;          // 4096 float4 tiles
            int r = f4 >> 5, c4 = f4 & 31;
            int node = row0 + r;
            float4 v = make_float4(0.f, 0.f, 0.f, 0.f);
            if (node < NN) v = *(const float4*)(x + (size_t)node * 128 + c4 * 4);
            xs[r][c4 * 4 + 0] = v.x;
            xs[r][c4 * 4 + 1] = v.y;
            xs[r][c4 * 4 + 2] = v.z;
            xs[r][c4 * 4 + 3] = v.w;
        }
    } else {
        // x1 lives interleaved in d_out: row stride 256, col stride 2
#pragma unroll 8
        for (int i = 0; i < 64; ++i) {
            int g = t + 256 * i;           // 16384 elements
            int r = g >> 7, c = g & 127;
            int node = row0 + r;
            float v = 0.f;
            if (node < NN) v = x[(size_t)node * 256 + c * 2];
            xs[r][c] = v;
        }
    }
    __syncthreads();
    const int nl = t & 63, q = t >> 6;
    float a0[32], a1[32];
#pragma unroll
    for (int j = 0; j < 32; ++j) { a0[j] = 0.f; a1[j] = 0.f; }
    const float* wq = W + q * 32;
#pragma unroll 2
    for (int k = 0; k < 128; ++k) {
        float x0 = xs[nl][k];
        float x1 = xs[nl + 64][k];
        const float4* w4 = (const float4*)(wq + (size_t)k * 128);
#pragma unroll
        for (int j4 = 0; j4 < 8; ++j4) {
            float4 wv = w4[j4];
            a0[j4 * 4 + 0] = fmaf(x0, wv.x, a0[j4 * 4 + 0]);
            a0[j4 * 4 + 1] = fmaf(x0, wv.y, a0[j4 * 4 + 1]);
            a0[j4 * 4 + 2] = fmaf(x0, wv.z, a0[j4 * 4 + 2]);
            a0[j4 * 4 + 3] = fmaf(x0, wv.w, a0[j4 * 4 + 3]);
            a1[j4 * 4 + 0] = fmaf(x1, wv.x, a1[j4 * 4 + 0]);
            a1[j4 * 4 + 1] = fmaf(x1, wv.y, a1[j4 * 4 + 1]);
            a1[j4 * 4 + 2] = fmaf(x1, wv.z, a1[j4 * 4 + 2]);
            a1[j4 * 4 + 3] = fmaf(x1, wv.w, a1[j4 * 4 + 3]);
        }
    }
#pragma unroll
    for (int half = 0; half < 2; ++half) {
        float* acc = half ? a1 : a0;
        int node = row0 + nl + half * 64;
        if (node < NN) {
            float as = 0.f, ad = 0.f;
#pragma unroll
            for (int j4 = 0; j4 < 8; ++j4) {
                float4 sv = *(const float4*)(atts + q * 32 + j4 * 4);
                float4 dv = *(const float4*)(attd + q * 32 + j4 * 4);
                as += acc[j4 * 4 + 0] * sv.x + acc[j4 * 4 + 1] * sv.y +
                      acc[j4 * 4 + 2] * sv.z + acc[j4 * 4 + 3] * sv.w;
                ad += acc[j4 * 4 + 0] * dv.x + acc[j4 * 4 + 1] * dv.y +
                      acc[j4 * 4 + 2] * dv.z + acc[j4 * 4 + 3] * dv.w;
                float4 hv = make_float4(acc[j4 * 4 + 0], acc[j4 * 4 + 1],
                                        acc[j4 * 4 + 2], acc[j4 * 4 + 3]);
                *(float4*)(h + (size_t)node * 128 + q * 32 + j4 * 4) = hv;
            }
            a_src[node * 4 + q] = as;
            a_dst[node * 4 + q] = ad;
        }
    }
}

// ---------------- per-node aggregation: single-pass online softmax ----------
// One wave per node. Per 16-edge chunk:
//   layout A: lane l = es*4+hh handles (edge ec+es, head hh) -> one gather
//   chunk max per head via 4x shfl_xor; rescale running (m, den, acc);
//   inner loop over edges: shfl-broadcast lk/src, exp, coalesced float2 h gather.
__global__ __launch_bounds__(256) void k_agg(
    const float* __restrict__ h,
    const float* __restrict__ a_src, const float* __restrict__ a_dst,
    const int* __restrict__ row_ptr, const int* __restrict__ src_sorted,
    const float* __restrict__ bias,
    float* __restrict__ out, int ors, int ocs) {
    const int lane = threadIdx.x & 63;
    const int node = blockIdx.x * 4 + (threadIdx.x >> 6);
    if (node >= NN) return;
    const int q = lane >> 4;       // head this lane accumulates (channels 2l,2l+1)
    const int hh = lane & 3;       // head this lane evaluates logits for
    const int es = lane >> 2;      // edge slot this lane evaluates logits for
    const int e0 = row_ptr[node], e1 = row_ptr[node + 1];
    const float advh = a_dst[node * 4 + hh];
    const float2* __restrict__ h2 = (const float2*)h;

    float m = -1e30f, den = 0.f, acc0 = 0.f, acc1 = 0.f;
    for (int ec = e0; ec < e1; ec += 16) {
        int nrem = e1 - ec;
        int cnt = nrem < 16 ? nrem : 16;
        int eidx = ec + es;
        if (eidx > e1 - 1) eidx = e1 - 1;
        int sv = src_sorted[eidx];
        float av = a_src[sv * 4 + hh];
        float lk = av + advh;
        lk = lk > 0.f ? lk : 0.2f * lk;
        if (es >= cnt) lk = -1e30f;
        // chunk max per head (reduce over es = bits 2..5)
        float cm = lk;
        cm = fmaxf(cm, __shfl_xor(cm, 4));
        cm = fmaxf(cm, __shfl_xor(cm, 8));
        cm = fmaxf(cm, __shfl_xor(cm, 16));
        cm = fmaxf(cm, __shfl_xor(cm, 32));
        float cmq = __shfl(cm, q);          // lane q holds head-q chunk max
        float mn = fmaxf(m, cmq);
        float scale = __expf(m - mn);       // first chunk: exp(-huge) -> 0, den/acc are 0
        den *= scale;
        acc0 *= scale;
        acc1 *= scale;
#pragma unroll
        for (int u = 0; u < 16; ++u) {
            if (u >= cnt) break;            // wave-uniform early exit
            float lku = __shfl(lk, (u << 2) + q);
            int su = __shfl(sv, u << 2);
            float ex = __expf(lku - mn);
            float2 hv = h2[(size_t)su * 64 + lane];
            den += ex;
            acc0 = fmaf(ex, hv.x, acc0);
            acc1 = fmaf(ex, hv.y, acc1);
        }
        m = mn;
    }
    float inv = den > 0.f ? 1.0f / den : 0.f;
    int c0 = lane * 2;
    float r0 = fmaxf(fmaf(acc0, inv, bias[c0]), 0.f);
    float r1 = fmaxf(fmaf(acc1, inv, bias[c0 + 1]), 0.f);
    out[(size_t)node * ors + (size_t)c0 * ocs] = r0;
    out[(size_t)node * ors + (size_t)(c0 + 1) * ocs] = r1;
}

// ---------------- launch ----------------

extern "C" void kernel_launch(void* const* d_in, const int* in_sizes, int n_in,
                              void* d_out, int out_size, void* d_ws, size_t ws_size,
                              hipStream_t stream) {
    const float* x   = (const float*)d_in[0];
    const int*   ei  = (const int*)d_in[1];
    const float* W1  = (const float*)d_in[2];
    const float* as1 = (const float*)d_in[3];
    const float* ad1 = (const float*)d_in[4];
    const float* b1  = (const float*)d_in[5];
    const float* W2  = (const float*)d_in[6];
    const float* as2 = (const float*)d_in[7];
    const float* ad2 = (const float*)d_in[8];
    const float* b2  = (const float*)d_in[9];
    float* out = (float*)d_out;
    const int* src = ei;
    const int* dst = ei + NE;

    char* w = (char*)d_ws;
    size_t off = 0;
    auto alloc = [&](size_t bytes) -> void* {
        void* p = w + off;
        off = (off + bytes + 255) & ~((size_t)255);
        return p;
    };
    float* h        = (float*)alloc((size_t)NN * 128 * 4);
    float* a_src    = (float*)alloc((size_t)NN * 4 * 4);
    float* a_dst    = (float*)alloc((size_t)NN * 4 * 4);
    int* counts     = (int*)alloc((size_t)NN * 4);
    int* row_ptr    = (int*)alloc((size_t)(NN + 1) * 4);
    int* nxt        = (int*)alloc((size_t)NN * 4);
    int* csum       = (int*)alloc(4096);
    int* src_sorted = (int*)alloc((size_t)NE * 4);

    const int nch = (NN + SCAN_CH - 1) / SCAN_CH;  // 98

    hipMemsetAsync(counts, 0, (size_t)NN * 4, stream);
    k_hist<<<(NE + 255) / 256, 256, 0, stream>>>(dst, counts);
    k_scan1<<<nch, 256, 0, stream>>>(counts, csum);
    k_scan2<<<1, 64, 0, stream>>>(csum, nch);
    k_scan3<<<nch, 256, 0, stream>>>(counts, csum, row_ptr, nxt);
    k_scatter<<<(NE + 255) / 256, 256, 0, stream>>>(src, dst, nxt, src_sorted);

    const int gemm_grid = (NN + 127) / 128;
    const int agg_grid = (NN + 3) / 4;

    k_gemm<<<gemm_grid, 256, 0, stream>>>(x, 0, W1, as1, ad1, h, a_src, a_dst);
    k_agg<<<agg_grid, 256, 0, stream>>>(h, a_src, a_dst, row_ptr, src_sorted, b1,
                                        out + 0, 256, 2);
    k_gemm<<<gemm_grid, 256, 0, stream>>>(out, 1, W2, as2, ad2, h, a_src, a_dst);
    k_agg<<<agg_grid, 256, 0, stream>>>(h, a_src, a_dst, row_ptr, src_sorted, b2,
                                        out + 1, 256, 2);
}

// Round 3
// 589.702 us; speedup vs baseline: 2.0551x; 1.3833x over previous
//
#include <hip/hip_runtime.h>

#define NN 100000
#define NE 1600000
#define SCAN_CH 1024

typedef short bf16x8 __attribute__((ext_vector_type(8)));
typedef float f32x4 __attribute__((ext_vector_type(4)));
typedef unsigned int u32;
typedef u32 u32x4 __attribute__((ext_vector_type(4)));

// ---------------- CSR build (dst-sorted edge lists) ----------------

__global__ __launch_bounds__(256) void k_hist(const int* __restrict__ dst,
                                              int* __restrict__ counts) {
    int e = blockIdx.x * 256 + threadIdx.x;
    if (e < NE) atomicAdd(&counts[dst[e]], 1);
}

__global__ __launch_bounds__(256) void k_scan1(const int* __restrict__ counts,
                                               int* __restrict__ csum) {
    __shared__ int sd[256];
    int t = threadIdx.x;
    int base = blockIdx.x * SCAN_CH + t * 4;
    int s = 0;
#pragma unroll
    for (int u = 0; u < 4; ++u) {
        int i = base + u;
        if (i < NN) s += counts[i];
    }
    sd[t] = s;
    __syncthreads();
    for (int off = 128; off > 0; off >>= 1) {
        if (t < off) sd[t] += sd[t + off];
        __syncthreads();
    }
    if (t == 0) csum[blockIdx.x] = sd[0];
}

__global__ __launch_bounds__(64) void k_scan2(int* csum, int nch) {
    if (threadIdx.x == 0 && blockIdx.x == 0) {
        int run = 0;
        for (int i = 0; i < nch; ++i) {
            int v = csum[i];
            csum[i] = run;
            run += v;
        }
    }
}

__global__ __launch_bounds__(256) void k_scan3(const int* __restrict__ counts,
                                               const int* __restrict__ csum,
                                               int* __restrict__ row_ptr,
                                               int* __restrict__ nxt) {
    __shared__ int sd[256];
    int t = threadIdx.x, b = blockIdx.x;
    int base = b * SCAN_CH + t * 4;
    int v[4];
    int s = 0;
#pragma unroll
    for (int u = 0; u < 4; ++u) {
        int i = base + u;
        v[u] = (i < NN) ? counts[i] : 0;
        s += v[u];
    }
    sd[t] = s;
    __syncthreads();
    for (int off = 1; off < 256; off <<= 1) {
        int x = (t >= off) ? sd[t - off] : 0;
        __syncthreads();
        sd[t] += x;
        __syncthreads();
    }
    int excl = (t == 0) ? 0 : sd[t - 1];
    int run = csum[b] + excl;
#pragma unroll
    for (int u = 0; u < 4; ++u) {
        int i = base + u;
        if (i < NN) {
            row_ptr[i] = run;
            nxt[i] = run;
        }
        run += v[u];
    }
    if (b == 0 && t == 0) row_ptr[NN] = NE;
}

__global__ __launch_bounds__(256) void k_scatter(const int* __restrict__ src,
                                                 const int* __restrict__ dst,
                                                 int* __restrict__ nxt,
                                                 int* __restrict__ src_sorted) {
    int e = blockIdx.x * 256 + threadIdx.x;
    if (e < NE) {
        int d = dst[e];
        int p = atomicAdd(&nxt[d], 1);
        src_sorted[p] = src[e];
    }
}

// ---------------- split-bf16 helpers ----------------
// f32 = hi(bf16,trunc) + lo(bf16,trunc); pack pairs into dwords (elem i = k+i).
__device__ inline void split_pack8(const float a[8], u32 hh[4], u32 ll[4]) {
#pragma unroll
    for (int j = 0; j < 4; ++j) {
        u32 u0 = __float_as_uint(a[2 * j]);
        u32 u1 = __float_as_uint(a[2 * j + 1]);
        float l0 = a[2 * j] - __uint_as_float(u0 & 0xFFFF0000u);
        float l1 = a[2 * j + 1] - __uint_as_float(u1 & 0xFFFF0000u);
        hh[j] = (u0 >> 16) | (u1 & 0xFFFF0000u);
        ll[j] = (__float_as_uint(l0) >> 16) | (__float_as_uint(l1) & 0xFFFF0000u);
    }
}

// W [128][128] row-major -> B-fragments for mfma_f32_16x16x32_bf16:
// frag (kc, ct), lane: col = lane&15, k = kc*32 + (lane>>4)*8 + i, i=0..7
__global__ __launch_bounds__(256) void k_wpack(const float* __restrict__ W,
                                               bf16x8* __restrict__ wpH,
                                               bf16x8* __restrict__ wpL) {
    int idx = blockIdx.x * 256 + threadIdx.x;  // 2048 = 4kc * 8ct * 64 lanes
    if (idx >= 2048) return;
    int lane = idx & 63, tile = idx >> 6;
    int kc = tile >> 3, ct = tile & 7;
    int col = lane & 15, kq = lane >> 4;
    int kbase = kc * 32 + kq * 8;
    float a[8];
#pragma unroll
    for (int i = 0; i < 8; ++i)
        a[i] = W[(size_t)(kbase + i) * 128 + ct * 16 + col];
    u32 hh[4], ll[4];
    split_pack8(a, hh, ll);
    wpH[tile * 64 + lane] = __builtin_bit_cast(bf16x8, (u32x4){hh[0], hh[1], hh[2], hh[3]});
    wpL[tile * 64 + lane] = __builtin_bit_cast(bf16x8, (u32x4){ll[0], ll[1], ll[2], ll[3]});
}

// ---------------- MFMA GEMM + attention-logit epilogue ----------------
// 64 nodes/block, 4 waves, wave w owns rows w*16..w*16+15 (full 128 cols).
// Split-bf16: acc += Ah*Bh + Al*Bh + Ah*Bl (f32 accumulate) -> ~2e-4 abs err.
__global__ __launch_bounds__(256) void k_gemm(
    const float* __restrict__ x, int strided2,
    const bf16x8* __restrict__ wpH, const bf16x8* __restrict__ wpL,
    const float* __restrict__ atts, const float* __restrict__ attd,
    float* __restrict__ h, float* __restrict__ a_src, float* __restrict__ a_dst) {
    __shared__ float xs[64][132];  // +4 pad: frag reads 2-way conflict (free)
    const int t = threadIdx.x;
    const int row0 = blockIdx.x * 64;
    if (!strided2) {
#pragma unroll
        for (int i = 0; i < 8; ++i) {
            int f4 = t + 256 * i;
            int r = f4 >> 5, c4 = f4 & 31;
            int node = row0 + r;
            float4 v = make_float4(0.f, 0.f, 0.f, 0.f);
            if (node < NN) v = *(const float4*)(x + (size_t)node * 128 + c4 * 4);
            *(float4*)&xs[r][c4 * 4] = v;
        }
    } else {
        // x1 interleaved in d_out: row stride 256, col stride 2
#pragma unroll
        for (int i = 0; i < 32; ++i) {
            int g = t + 256 * i;
            int r = g >> 7, c = g & 127;
            int node = row0 + r;
            xs[r][c] = (node < NN) ? x[(size_t)node * 256 + c * 2] : 0.f;
        }
    }
    __syncthreads();
    const int lane = t & 63;
    const int w = t >> 6;
    const int col = lane & 15, kq = lane >> 4;
    f32x4 acc[8];
#pragma unroll
    for (int ct = 0; ct < 8; ++ct) acc[ct] = (f32x4){0.f, 0.f, 0.f, 0.f};
#pragma unroll
    for (int kc = 0; kc < 4; ++kc) {
        // A-frag: row = lane&15, k = kc*32 + (lane>>4)*8 + i
        const float* ap = &xs[w * 16 + col][kc * 32 + kq * 8];
        float a[8];
        *(float4*)&a[0] = *(const float4*)ap;
        *(float4*)&a[4] = *(const float4*)(ap + 4);
        u32 hh[4], ll[4];
        split_pack8(a, hh, ll);
        bf16x8 ah = __builtin_bit_cast(bf16x8, (u32x4){hh[0], hh[1], hh[2], hh[3]});
        bf16x8 al = __builtin_bit_cast(bf16x8, (u32x4){ll[0], ll[1], ll[2], ll[3]});
#pragma unroll
        for (int ct = 0; ct < 8; ++ct) {
            bf16x8 bh = wpH[(kc * 8 + ct) * 64 + lane];
            bf16x8 bl = wpL[(kc * 8 + ct) * 64 + lane];
            acc[ct] = __builtin_amdgcn_mfma_f32_16x16x32_bf16(ah, bh, acc[ct], 0, 0, 0);
            acc[ct] = __builtin_amdgcn_mfma_f32_16x16x32_bf16(al, bh, acc[ct], 0, 0, 0);
            acc[ct] = __builtin_amdgcn_mfma_f32_16x16x32_bf16(ah, bl, acc[ct], 0, 0, 0);
        }
    }
    // epilogue: D layout col=lane&15, row=(lane>>4)*4+reg
    float as0[4], as1[4], ad0[4], ad1[4];
#pragma unroll
    for (int q = 0; q < 4; ++q) {
        as0[q] = atts[q * 32 + col];
        as1[q] = atts[q * 32 + 16 + col];
        ad0[q] = attd[q * 32 + col];
        ad1[q] = attd[q * 32 + 16 + col];
    }
#pragma unroll
    for (int r = 0; r < 4; ++r) {
        int node = row0 + w * 16 + kq * 4 + r;
        float ps[4], pd[4];
#pragma unroll
        for (int q = 0; q < 4; ++q) {
            float d0 = acc[2 * q][r], d1 = acc[2 * q + 1][r];
            ps[q] = d0 * as0[q] + d1 * as1[q];
            pd[q] = d0 * ad0[q] + d1 * ad1[q];
        }
#pragma unroll
        for (int off = 1; off < 16; off <<= 1) {
#pragma unroll
            for (int q = 0; q < 4; ++q) {
                ps[q] += __shfl_xor(ps[q], off);
                pd[q] += __shfl_xor(pd[q], off);
            }
        }
        if (node < NN) {
#pragma unroll
            for (int ct = 0; ct < 8; ++ct)
                h[(size_t)node * 128 + ct * 16 + col] = acc[ct][r];
            if (col < 4) {
                float vs = col == 0 ? ps[0] : col == 1 ? ps[1] : col == 2 ? ps[2] : ps[3];
                float vd = col == 0 ? pd[0] : col == 1 ? pd[1] : col == 2 ? pd[2] : pd[3];
                a_src[node * 4 + col] = vs;
                a_dst[node * 4 + col] = vd;
            }
        }
    }
}

// ---------------- per-node aggregation: single-pass online softmax ----------
__global__ __launch_bounds__(256) void k_agg(
    const float* __restrict__ h,
    const float* __restrict__ a_src, const float* __restrict__ a_dst,
    const int* __restrict__ row_ptr, const int* __restrict__ src_sorted,
    const float* __restrict__ bias,
    float* __restrict__ out, int ors, int ocs) {
    const int lane = threadIdx.x & 63;
    const int node = blockIdx.x * 4 + (threadIdx.x >> 6);
    if (node >= NN) return;
    const int q = lane >> 4;       // head this lane accumulates (channels 2l,2l+1)
    const int hh = lane & 3;       // head this lane evaluates logits for
    const int es = lane >> 2;      // edge slot this lane evaluates logits for
    const int e0 = row_ptr[node], e1 = row_ptr[node + 1];
    const float advh = a_dst[node * 4 + hh];
    const float2* __restrict__ h2 = (const float2*)h;

    float m = -1e30f, den = 0.f, acc0 = 0.f, acc1 = 0.f;
    for (int ec = e0; ec < e1; ec += 16) {
        int nrem = e1 - ec;
        int cnt = nrem < 16 ? nrem : 16;
        int eidx = ec + es;
        if (eidx > e1 - 1) eidx = e1 - 1;
        int sv = src_sorted[eidx];
        float av = a_src[sv * 4 + hh];
        float lk = av + advh;
        lk = lk > 0.f ? lk : 0.2f * lk;
        if (es >= cnt) lk = -1e30f;
        float cm = lk;
        cm = fmaxf(cm, __shfl_xor(cm, 4));
        cm = fmaxf(cm, __shfl_xor(cm, 8));
        cm = fmaxf(cm, __shfl_xor(cm, 16));
        cm = fmaxf(cm, __shfl_xor(cm, 32));
        float cmq = __shfl(cm, q);
        float mn = fmaxf(m, cmq);
        float scale = __expf(m - mn);
        den *= scale;
        acc0 *= scale;
        acc1 *= scale;
#pragma unroll
        for (int u = 0; u < 16; ++u) {
            if (u >= cnt) break;
            float lku = __shfl(lk, (u << 2) + q);
            int su = __shfl(sv, u << 2);
            float ex = __expf(lku - mn);
            float2 hv = h2[(size_t)su * 64 + lane];
            den += ex;
            acc0 = fmaf(ex, hv.x, acc0);
            acc1 = fmaf(ex, hv.y, acc1);
        }
        m = mn;
    }
    float inv = den > 0.f ? 1.0f / den : 0.f;
    int c0 = lane * 2;
    float r0 = fmaxf(fmaf(acc0, inv, bias[c0]), 0.f);
    float r1 = fmaxf(fmaf(acc1, inv, bias[c0 + 1]), 0.f);
    out[(size_t)node * ors + (size_t)c0 * ocs] = r0;
    out[(size_t)node * ors + (size_t)(c0 + 1) * ocs] = r1;
}

// ---------------- launch ----------------

extern "C" void kernel_launch(void* const* d_in, const int* in_sizes, int n_in,
                              void* d_out, int out_size, void* d_ws, size_t ws_size,
                              hipStream_t stream) {
    const float* x   = (const float*)d_in[0];
    const int*   ei  = (const int*)d_in[1];
    const float* W1  = (const float*)d_in[2];
    const float* as1 = (const float*)d_in[3];
    const float* ad1 = (const float*)d_in[4];
    const float* b1  = (const float*)d_in[5];
    const float* W2  = (const float*)d_in[6];
    const float* as2 = (const float*)d_in[7];
    const float* ad2 = (const float*)d_in[8];
    const float* b2  = (const float*)d_in[9];
    float* out = (float*)d_out;
    const int* src = ei;
    const int* dst = ei + NE;

    char* w = (char*)d_ws;
    size_t off = 0;
    auto alloc = [&](size_t bytes) -> void* {
        void* p = w + off;
        off = (off + bytes + 255) & ~((size_t)255);
        return p;
    };
    float* h        = (float*)alloc((size_t)NN * 128 * 4);
    float* a_src    = (float*)alloc((size_t)NN * 4 * 4);
    float* a_dst    = (float*)alloc((size_t)NN * 4 * 4);
    int* counts     = (int*)alloc((size_t)NN * 4);
    int* row_ptr    = (int*)alloc((size_t)(NN + 1) * 4);
    int* nxt        = (int*)alloc((size_t)NN * 4);
    int* csum       = (int*)alloc(4096);
    int* src_sorted = (int*)alloc((size_t)NE * 4);
    bf16x8* wpH1    = (bf16x8*)alloc(2048 * 16);
    bf16x8* wpL1    = (bf16x8*)alloc(2048 * 16);
    bf16x8* wpH2    = (bf16x8*)alloc(2048 * 16);
    bf16x8* wpL2    = (bf16x8*)alloc(2048 * 16);

    const int nch = (NN + SCAN_CH - 1) / SCAN_CH;  // 98

    k_wpack<<<8, 256, 0, stream>>>(W1, wpH1, wpL1);
    k_wpack<<<8, 256, 0, stream>>>(W2, wpH2, wpL2);

    hipMemsetAsync(counts, 0, (size_t)NN * 4, stream);
    k_hist<<<(NE + 255) / 256, 256, 0, stream>>>(dst, counts);
    k_scan1<<<nch, 256, 0, stream>>>(counts, csum);
    k_scan2<<<1, 64, 0, stream>>>(csum, nch);
    k_scan3<<<nch, 256, 0, stream>>>(counts, csum, row_ptr, nxt);
    k_scatter<<<(NE + 255) / 256, 256, 0, stream>>>(src, dst, nxt, src_sorted);

    const int gemm_grid = (NN + 63) / 64;
    const int agg_grid = (NN + 3) / 4;

    k_gemm<<<gemm_grid, 256, 0, stream>>>(x, 0, wpH1, wpL1, as1, ad1, h, a_src, a_dst);
    k_agg<<<agg_grid, 256, 0, stream>>>(h, a_src, a_dst, row_ptr, src_sorted, b1,
                                        out + 0, 256, 2);
    k_gemm<<<gemm_grid, 256, 0, stream>>>(out, 1, wpH2, wpL2, as2, ad2, h, a_src, a_dst);
    k_agg<<<agg_grid, 256, 0, stream>>>(h, a_src, a_dst, row_ptr, src_sorted, b2,
                                        out + 1, 256, 2);
}

// Round 5
// 488.786 us; speedup vs baseline: 2.4794x; 1.2065x over previous
//
#include <hip/hip_runtime.h>

#define NN 100000
#define NE 1600000
#define SCAN_CH 1024

typedef short bf16x8 __attribute__((ext_vector_type(8)));
typedef float f32x4 __attribute__((ext_vector_type(4)));
typedef unsigned int u32;
typedef u32 u32x4 __attribute__((ext_vector_type(4)));
typedef unsigned short u16;

__device__ inline u32 bf16r(float x) {  // RTNE bf16, returns low-16 bits
    u32 u = __float_as_uint(x);
    return (u + 0x7FFFu + ((u >> 16) & 1u)) >> 16;
}

// ---------------- CSR build (dst-sorted edge lists) ----------------

__global__ __launch_bounds__(256) void k_hist(const int* __restrict__ dst,
                                              int* __restrict__ counts) {
    int e = blockIdx.x * 256 + threadIdx.x;
    if (e < NE) atomicAdd(&counts[dst[e]], 1);
}

__global__ __launch_bounds__(256) void k_scan1(const int* __restrict__ counts,
                                               int* __restrict__ csum) {
    __shared__ int sd[256];
    int t = threadIdx.x;
    int base = blockIdx.x * SCAN_CH + t * 4;
    int s = 0;
#pragma unroll
    for (int u = 0; u < 4; ++u) {
        int i = base + u;
        if (i < NN) s += counts[i];
    }
    sd[t] = s;
    __syncthreads();
    for (int off = 128; off > 0; off >>= 1) {
        if (t < off) sd[t] += sd[t + off];
        __syncthreads();
    }
    if (t == 0) csum[blockIdx.x] = sd[0];
}

__global__ __launch_bounds__(64) void k_scan2(int* csum, int nch) {
    if (threadIdx.x == 0 && blockIdx.x == 0) {
        int run = 0;
        for (int i = 0; i < nch; ++i) {
            int v = csum[i];
            csum[i] = run;
            run += v;
        }
    }
}

__global__ __launch_bounds__(256) void k_scan3(const int* __restrict__ counts,
                                               const int* __restrict__ csum,
                                               int* __restrict__ row_ptr,
                                               int* __restrict__ nxt) {
    __shared__ int sd[256];
    int t = threadIdx.x, b = blockIdx.x;
    int base = b * SCAN_CH + t * 4;
    int v[4];
    int s = 0;
#pragma unroll
    for (int u = 0; u < 4; ++u) {
        int i = base + u;
        v[u] = (i < NN) ? counts[i] : 0;
        s += v[u];
    }
    sd[t] = s;
    __syncthreads();
    for (int off = 1; off < 256; off <<= 1) {
        int x = (t >= off) ? sd[t - off] : 0;
        __syncthreads();
        sd[t] += x;
        __syncthreads();
    }
    int excl = (t == 0) ? 0 : sd[t - 1];
    int run = csum[b] + excl;
#pragma unroll
    for (int u = 0; u < 4; ++u) {
        int i = base + u;
        if (i < NN) {
            row_ptr[i] = run;
            nxt[i] = run;
        }
        run += v[u];
    }
    if (b == 0 && t == 0) row_ptr[NN] = NE;
}

__global__ __launch_bounds__(256) void k_scatter(const int* __restrict__ src,
                                                 const int* __restrict__ dst,
                                                 int* __restrict__ nxt,
                                                 int* __restrict__ src_sorted) {
    int e = blockIdx.x * 256 + threadIdx.x;
    if (e < NE) {
        int d = dst[e];
        int p = atomicAdd(&nxt[d], 1);
        src_sorted[p] = src[e];
    }
}

// ---------------- split-bf16 helpers ----------------
__device__ inline void split_pack8(const float a[8], u32 hh[4], u32 ll[4]) {
#pragma unroll
    for (int j = 0; j < 4; ++j) {
        u32 u0 = __float_as_uint(a[2 * j]);
        u32 u1 = __float_as_uint(a[2 * j + 1]);
        float l0 = a[2 * j] - __uint_as_float(u0 & 0xFFFF0000u);
        float l1 = a[2 * j + 1] - __uint_as_float(u1 & 0xFFFF0000u);
        hh[j] = (u0 >> 16) | (u1 & 0xFFFF0000u);
        ll[j] = (__float_as_uint(l0) >> 16) | (__float_as_uint(l1) & 0xFFFF0000u);
    }
}

// W [128][128] row-major -> B-fragments for mfma_f32_16x16x32_bf16
__global__ __launch_bounds__(256) void k_wpack(const float* __restrict__ W,
                                               bf16x8* __restrict__ wpH,
                                               bf16x8* __restrict__ wpL) {
    int idx = blockIdx.x * 256 + threadIdx.x;  // 2048 = 4kc * 8ct * 64 lanes
    if (idx >= 2048) return;
    int lane = idx & 63, tile = idx >> 6;
    int kc = tile >> 3, ct = tile & 7;
    int col = lane & 15, kq = lane >> 4;
    int kbase = kc * 32 + kq * 8;
    float a[8];
#pragma unroll
    for (int i = 0; i < 8; ++i)
        a[i] = W[(size_t)(kbase + i) * 128 + ct * 16 + col];
    u32 hh[4], ll[4];
    split_pack8(a, hh, ll);
    wpH[tile * 64 + lane] = __builtin_bit_cast(bf16x8, (u32x4){hh[0], hh[1], hh[2], hh[3]});
    wpL[tile * 64 + lane] = __builtin_bit_cast(bf16x8, (u32x4){ll[0], ll[1], ll[2], ll[3]});
}

// shared GEMM epilogue: h (bf16) + attention logits
__device__ inline void gemm_epilogue(f32x4 acc[8], int row0, int w, int col, int kq,
                                     const float* __restrict__ atts,
                                     const float* __restrict__ attd,
                                     u16* __restrict__ hb,
                                     float* __restrict__ a_src,
                                     float* __restrict__ a_dst) {
    float as0[4], as1[4], ad0[4], ad1[4];
#pragma unroll
    for (int q = 0; q < 4; ++q) {
        as0[q] = atts[q * 32 + col];
        as1[q] = atts[q * 32 + 16 + col];
        ad0[q] = attd[q * 32 + col];
        ad1[q] = attd[q * 32 + 16 + col];
    }
#pragma unroll
    for (int r = 0; r < 4; ++r) {
        int node = row0 + w * 16 + kq * 4 + r;
        float ps[4], pd[4];
#pragma unroll
        for (int q = 0; q < 4; ++q) {
            float d0 = acc[2 * q][r], d1 = acc[2 * q + 1][r];
            ps[q] = d0 * as0[q] + d1 * as1[q];
            pd[q] = d0 * ad0[q] + d1 * ad1[q];
        }
#pragma unroll
        for (int off = 1; off < 16; off <<= 1) {
#pragma unroll
            for (int q = 0; q < 4; ++q) {
                ps[q] += __shfl_xor(ps[q], off);
                pd[q] += __shfl_xor(pd[q], off);
            }
        }
        if (node < NN) {
#pragma unroll
            for (int ct = 0; ct < 8; ++ct)
                hb[(size_t)node * 128 + ct * 16 + col] = (u16)bf16r(acc[ct][r]);
            if (col < 4) {
                float vs = col == 0 ? ps[0] : col == 1 ? ps[1] : col == 2 ? ps[2] : ps[3];
                float vd = col == 0 ? pd[0] : col == 1 ? pd[1] : col == 2 ? pd[2] : pd[3];
                a_src[node * 4 + col] = vs;
                a_dst[node * 4 + col] = vd;
            }
        }
    }
}

// ---------------- GEMM layer 1: f32 input, split-bf16 A and B ----------------
__global__ __launch_bounds__(256) void k_gemm1(
    const float* __restrict__ x,
    const bf16x8* __restrict__ wpH, const bf16x8* __restrict__ wpL,
    const float* __restrict__ atts, const float* __restrict__ attd,
    u16* __restrict__ hb, float* __restrict__ a_src, float* __restrict__ a_dst) {
    __shared__ __align__(16) float xs[64][132];
    const int t = threadIdx.x;
    const int row0 = blockIdx.x * 64;
#pragma unroll
    for (int i = 0; i < 8; ++i) {
        int f4 = t + 256 * i;
        int r = f4 >> 5, c4 = f4 & 31;
        int node = row0 + r;
        float4 v = make_float4(0.f, 0.f, 0.f, 0.f);
        if (node < NN) v = *(const float4*)(x + (size_t)node * 128 + c4 * 4);
        *(float4*)&xs[r][c4 * 4] = v;
    }
    __syncthreads();
    const int lane = t & 63;
    const int w = t >> 6;
    const int col = lane & 15, kq = lane >> 4;
    f32x4 acc[8];
#pragma unroll
    for (int ct = 0; ct < 8; ++ct) acc[ct] = (f32x4){0.f, 0.f, 0.f, 0.f};
#pragma unroll
    for (int kc = 0; kc < 4; ++kc) {
        const float* ap = &xs[w * 16 + col][kc * 32 + kq * 8];
        float a[8];
        *(float4*)&a[0] = *(const float4*)ap;
        *(float4*)&a[4] = *(const float4*)(ap + 4);
        u32 hh[4], ll[4];
        split_pack8(a, hh, ll);
        bf16x8 ah = __builtin_bit_cast(bf16x8, (u32x4){hh[0], hh[1], hh[2], hh[3]});
        bf16x8 al = __builtin_bit_cast(bf16x8, (u32x4){ll[0], ll[1], ll[2], ll[3]});
#pragma unroll
        for (int ct = 0; ct < 8; ++ct) {
            bf16x8 bh = wpH[(kc * 8 + ct) * 64 + lane];
            bf16x8 bl = wpL[(kc * 8 + ct) * 64 + lane];
            acc[ct] = __builtin_amdgcn_mfma_f32_16x16x32_bf16(ah, bh, acc[ct], 0, 0, 0);
            acc[ct] = __builtin_amdgcn_mfma_f32_16x16x32_bf16(al, bh, acc[ct], 0, 0, 0);
            acc[ct] = __builtin_amdgcn_mfma_f32_16x16x32_bf16(ah, bl, acc[ct], 0, 0, 0);
        }
    }
    gemm_epilogue(acc, row0, w, col, kq, atts, attd, hb, a_src, a_dst);
}

// ---------------- GEMM layer 2: bf16 input (exact A), split B ----------------
__global__ __launch_bounds__(256) void k_gemm2(
    const u32* __restrict__ xb,   // [NN][64] bf16 pairs (ch 2j low, 2j+1 high)
    const bf16x8* __restrict__ wpH, const bf16x8* __restrict__ wpL,
    const float* __restrict__ atts, const float* __restrict__ attd,
    u16* __restrict__ hb, float* __restrict__ a_src, float* __restrict__ a_dst) {
    __shared__ __align__(16) u32 xs[64][68];
    const int t = threadIdx.x;
    const int row0 = blockIdx.x * 64;
#pragma unroll
    for (int i = 0; i < 16; ++i) {
        int idx = t + 256 * i;
        int r = idx >> 6, c = idx & 63;
        int node = row0 + r;
        xs[r][c] = (node < NN) ? xb[node * 64 + c] : 0u;
    }
    __syncthreads();
    const int lane = t & 63;
    const int w = t >> 6;
    const int col = lane & 15, kq = lane >> 4;
    f32x4 acc[8];
#pragma unroll
    for (int ct = 0; ct < 8; ++ct) acc[ct] = (f32x4){0.f, 0.f, 0.f, 0.f};
#pragma unroll
    for (int kc = 0; kc < 4; ++kc) {
        const u32* ap = &xs[w * 16 + col][kc * 16 + kq * 4];
        int4 aw = *(const int4*)ap;
        bf16x8 a = __builtin_bit_cast(bf16x8, aw);
#pragma unroll
        for (int ct = 0; ct < 8; ++ct) {
            bf16x8 bh = wpH[(kc * 8 + ct) * 64 + lane];
            bf16x8 bl = wpL[(kc * 8 + ct) * 64 + lane];
            acc[ct] = __builtin_amdgcn_mfma_f32_16x16x32_bf16(a, bh, acc[ct], 0, 0, 0);
            acc[ct] = __builtin_amdgcn_mfma_f32_16x16x32_bf16(a, bl, acc[ct], 0, 0, 0);
        }
    }
    gemm_epilogue(acc, row0, w, col, kq, atts, attd, hb, a_src, a_dst);
}

// ---------------- aggregation: static-max softmax, bf16 gathers ----------------
// One wave per node. Head-major lanes: q = lane>>4 (head), es = lane&15 (edge
// slot). Per 16-edge chunk: one vectorized exp for all (head, slot) pairs;
// inner loop per edge: shfl broadcast of ex (lane = head-base | u) + readlane
// src + 4 B bf16-pair gather + 2 fma. Denominator reduced once per node.
#define AGG_BODY(GUARD)                                                        \
    for (int u = 0; u < 16; ++u) {                                             \
        GUARD                                                                  \
        float exu = __shfl(ex, hbase | u);                                     \
        int su = __builtin_amdgcn_readlane(sv, u);                             \
        u32 wv = hb[su * 64 + lane];                                           \
        float h0 = __uint_as_float(wv << 16);                                  \
        float h1 = __uint_as_float(wv & 0xFFFF0000u);                          \
        if (u & 1) { a0b = fmaf(exu, h0, a0b); a1b = fmaf(exu, h1, a1b); }     \
        else       { a0a = fmaf(exu, h0, a0a); a1a = fmaf(exu, h1, a1a); }     \
    }

__global__ __launch_bounds__(256) void k_agg(
    const u32* __restrict__ hb,   // [NN][64] bf16 pairs
    const float* __restrict__ a_src, const float* __restrict__ a_dst,
    const int* __restrict__ row_ptr, const int* __restrict__ src_sorted,
    const float* __restrict__ bias,
    u32* __restrict__ x1b, float* __restrict__ outp, int layer) {
    const int lane = threadIdx.x & 63;
    const int node = blockIdx.x * 4 + (threadIdx.x >> 6);
    if (node >= NN) return;
    const int q = lane >> 4;
    const int es = lane & 15;
    const int hbase = lane & 48;
    const int e0 = row_ptr[node], e1 = row_ptr[node + 1];
    const float advh = a_dst[node * 4 + q];
    float den = 0.f, a0a = 0.f, a0b = 0.f, a1a = 0.f, a1b = 0.f;
    for (int ec = e0; ec < e1; ec += 16) {
        int cnt = e1 - ec;
        cnt = cnt < 16 ? cnt : 16;
        int eidx = ec + es;
        int emax = e1 - 1;
        if (eidx > emax) eidx = emax;
        int sv = src_sorted[eidx];
        float av = a_src[sv * 4 + q];
        float lk = av + advh;
        lk = lk > 0.f ? lk : 0.2f * lk;
        float ex = (es < cnt) ? __expf(lk - 8.f) : 0.f;
        den += ex;
        if (cnt == 16) {
#pragma unroll
            AGG_BODY(;)
        } else {
#pragma unroll
            AGG_BODY(if (u >= cnt) break;)
        }
    }
    float a0 = a0a + a0b, a1 = a1a + a1b;
#pragma unroll
    for (int m = 1; m < 16; m <<= 1) den += __shfl_xor(den, m);
    float inv = den > 0.f ? 1.f / den : 0.f;
    int c0 = lane * 2;
    float r0 = fmaxf(fmaf(a0, inv, bias[c0]), 0.f);
    float r1 = fmaxf(fmaf(a1, inv, bias[c0 + 1]), 0.f);
    if (layer == 1) {
        x1b[node * 64 + lane] = bf16r(r0) | (bf16r(r1) << 16);
    } else {
        u32 w1 = x1b[node * 64 + lane];
        float4 o;
        o.x = __uint_as_float(w1 << 16);          // x1[2l]
        o.y = r0;                                  // x2[2l]
        o.z = __uint_as_float(w1 & 0xFFFF0000u);  // x1[2l+1]
        o.w = r1;                                  // x2[2l+1]
        *(float4*)(outp + (size_t)node * 256 + lane * 4) = o;
    }
}

// ---------------- launch ----------------

extern "C" void kernel_launch(void* const* d_in, const int* in_sizes, int n_in,
                              void* d_out, int out_size, void* d_ws, size_t ws_size,
                              hipStream_t stream) {
    const float* x   = (const float*)d_in[0];
    const int*   ei  = (const int*)d_in[1];
    const float* W1  = (const float*)d_in[2];
    const float* as1 = (const float*)d_in[3];
    const float* ad1 = (const float*)d_in[4];
    const float* b1  = (const float*)d_in[5];
    const float* W2  = (const float*)d_in[6];
    const float* as2 = (const float*)d_in[7];
    const float* ad2 = (const float*)d_in[8];
    const float* b2  = (const float*)d_in[9];
    float* out = (float*)d_out;
    const int* src = ei;
    const int* dst = ei + NE;

    char* w = (char*)d_ws;
    size_t off = 0;
    auto alloc = [&](size_t bytes) -> void* {
        void* p = w + off;
        off = (off + bytes + 255) & ~((size_t)255);
        return p;
    };
    u16* hb         = (u16*)alloc((size_t)NN * 128 * 2);   // h as bf16
    u32* x1b        = (u32*)alloc((size_t)NN * 64 * 4);    // x1 as bf16 pairs
    float* a_src    = (float*)alloc((size_t)NN * 4 * 4);
    float* a_dst    = (float*)alloc((size_t)NN * 4 * 4);
    int* counts     = (int*)alloc((size_t)NN * 4);
    int* row_ptr    = (int*)alloc((size_t)(NN + 1) * 4);
    int* nxt        = (int*)alloc((size_t)NN * 4);
    int* csum       = (int*)alloc(4096);
    int* src_sorted = (int*)alloc((size_t)NE * 4);
    bf16x8* wpH1    = (bf16x8*)alloc(2048 * 16);
    bf16x8* wpL1    = (bf16x8*)alloc(2048 * 16);
    bf16x8* wpH2    = (bf16x8*)alloc(2048 * 16);
    bf16x8* wpL2    = (bf16x8*)alloc(2048 * 16);

    const int nch = (NN + SCAN_CH - 1) / SCAN_CH;  // 98

    k_wpack<<<8, 256, 0, stream>>>(W1, wpH1, wpL1);
    k_wpack<<<8, 256, 0, stream>>>(W2, wpH2, wpL2);

    (void)hipMemsetAsync(counts, 0, (size_t)NN * 4, stream);
    k_hist<<<(NE + 255) / 256, 256, 0, stream>>>(dst, counts);
    k_scan1<<<nch, 256, 0, stream>>>(counts, csum);
    k_scan2<<<1, 64, 0, stream>>>(csum, nch);
    k_scan3<<<nch, 256, 0, stream>>>(counts, csum, row_ptr, nxt);
    k_scatter<<<(NE + 255) / 256, 256, 0, stream>>>(src, dst, nxt, src_sorted);

    const int gemm_grid = (NN + 63) / 64;
    const int agg_grid = (NN + 3) / 4;

    k_gemm1<<<gemm_grid, 256, 0, stream>>>(x, wpH1, wpL1, as1, ad1, hb, a_src, a_dst);
    k_agg<<<agg_grid, 256, 0, stream>>>((const u32*)hb, a_src, a_dst, row_ptr,
                                        src_sorted, b1, x1b, out, 1);
    k_gemm2<<<gemm_grid, 256, 0, stream>>>(x1b, wpH2, wpL2, as2, ad2, hb, a_src, a_dst);
    k_agg<<<agg_grid, 256, 0, stream>>>((const u32*)hb, a_src, a_dst, row_ptr,
                                        src_sorted, b2, x1b, out, 2);
}

// Round 6
// 376.878 us; speedup vs baseline: 3.2156x; 1.2969x over previous
//
#include <hip/hip_runtime.h>

#define NN 100000
#define NE 1600000
#define SCAN_CH 1024
#define GEMM_GRID 1563            // ceil(NN/64)
#define SCAT_GRID 6250            // NE/256
#define SG_GRID (GEMM_GRID + SCAT_GRID)
#define WH_GRID (16 + SCAT_GRID)  // wpack x2 + hist

typedef short bf16x8 __attribute__((ext_vector_type(8)));
typedef float f32x4 __attribute__((ext_vector_type(4)));
typedef unsigned int u32;
typedef u32 u32x4 __attribute__((ext_vector_type(4)));
typedef unsigned short u16;

__device__ inline u32 bf16r(float x) {  // RTNE bf16, returns low-16 bits
    u32 u = __float_as_uint(x);
    return (u + 0x7FFFu + ((u >> 16) & 1u)) >> 16;
}

// ---------------- split-bf16 helpers ----------------
__device__ inline void split_pack8(const float a[8], u32 hh[4], u32 ll[4]) {
#pragma unroll
    for (int j = 0; j < 4; ++j) {
        u32 u0 = __float_as_uint(a[2 * j]);
        u32 u1 = __float_as_uint(a[2 * j + 1]);
        float l0 = a[2 * j] - __uint_as_float(u0 & 0xFFFF0000u);
        float l1 = a[2 * j + 1] - __uint_as_float(u1 & 0xFFFF0000u);
        hh[j] = (u0 >> 16) | (u1 & 0xFFFF0000u);
        ll[j] = (__float_as_int(l0) >> 16 & 0xFFFFu) | (__float_as_uint(l1) & 0xFFFF0000u);
    }
}

__device__ inline void wpack_body(int idx, const float* __restrict__ W,
                                  bf16x8* __restrict__ wpH, bf16x8* __restrict__ wpL) {
    if (idx >= 2048) return;
    int lane = idx & 63, tile = idx >> 6;
    int kc = tile >> 3, ct = tile & 7;
    int col = lane & 15, kq = lane >> 4;
    int kbase = kc * 32 + kq * 8;
    float a[8];
#pragma unroll
    for (int i = 0; i < 8; ++i)
        a[i] = W[(size_t)(kbase + i) * 128 + ct * 16 + col];
    u32 hh[4], ll[4];
    split_pack8(a, hh, ll);
    wpH[tile * 64 + lane] = __builtin_bit_cast(bf16x8, (u32x4){hh[0], hh[1], hh[2], hh[3]});
    wpL[tile * 64 + lane] = __builtin_bit_cast(bf16x8, (u32x4){ll[0], ll[1], ll[2], ll[3]});
}

// ---------------- fused: wpack(W1) | wpack(W2) | hist+occ ----------------
__global__ __launch_bounds__(256) void k_wh(
    const float* __restrict__ W1, bf16x8* __restrict__ wpH1, bf16x8* __restrict__ wpL1,
    const float* __restrict__ W2, bf16x8* __restrict__ wpH2, bf16x8* __restrict__ wpL2,
    const int* __restrict__ dst, int* __restrict__ counts, int* __restrict__ occ) {
    int b = blockIdx.x;
    if (b < 8) {
        wpack_body(b * 256 + threadIdx.x, W1, wpH1, wpL1);
    } else if (b < 16) {
        wpack_body((b - 8) * 256 + threadIdx.x, W2, wpH2, wpL2);
    } else {
        int e = (b - 16) * 256 + threadIdx.x;
        if (e < NE) occ[e] = atomicAdd(&counts[dst[e]], 1);
    }
}

// ---------------- scans ----------------
__global__ __launch_bounds__(256) void k_scan1(const int* __restrict__ counts,
                                               int* __restrict__ csum) {
    __shared__ int sd[256];
    int t = threadIdx.x;
    int base = blockIdx.x * SCAN_CH + t * 4;
    int s = 0;
#pragma unroll
    for (int u = 0; u < 4; ++u) {
        int i = base + u;
        if (i < NN) s += counts[i];
    }
    sd[t] = s;
    __syncthreads();
    for (int off = 128; off > 0; off >>= 1) {
        if (t < off) sd[t] += sd[t + off];
        __syncthreads();
    }
    if (t == 0) csum[blockIdx.x] = sd[0];
}

__global__ __launch_bounds__(64) void k_scan2(int* csum, int nch) {
    if (threadIdx.x == 0 && blockIdx.x == 0) {
        int run = 0;
        for (int i = 0; i < nch; ++i) {
            int v = csum[i];
            csum[i] = run;
            run += v;
        }
    }
}

__global__ __launch_bounds__(256) void k_scan3(const int* __restrict__ counts,
                                               const int* __restrict__ csum,
                                               int* __restrict__ row_ptr) {
    __shared__ int sd[256];
    int t = threadIdx.x, b = blockIdx.x;
    int base = b * SCAN_CH + t * 4;
    int v[4];
    int s = 0;
#pragma unroll
    for (int u = 0; u < 4; ++u) {
        int i = base + u;
        v[u] = (i < NN) ? counts[i] : 0;
        s += v[u];
    }
    sd[t] = s;
    __syncthreads();
    for (int off = 1; off < 256; off <<= 1) {
        int x = (t >= off) ? sd[t - off] : 0;
        __syncthreads();
        sd[t] += x;
        __syncthreads();
    }
    int excl = (t == 0) ? 0 : sd[t - 1];
    int run = csum[b] + excl;
#pragma unroll
    for (int u = 0; u < 4; ++u) {
        int i = base + u;
        if (i < NN) row_ptr[i] = run;
        run += v[u];
    }
    if (b == 0 && t == 0) row_ptr[NN] = NE;
}

// shared GEMM epilogue: h (bf16) + attention logits
__device__ inline void gemm_epilogue(f32x4 acc[8], int row0, int w, int col, int kq,
                                     const float* __restrict__ atts,
                                     const float* __restrict__ attd,
                                     u16* __restrict__ hb,
                                     float* __restrict__ a_src,
                                     float* __restrict__ a_dst) {
    float as0[4], as1[4], ad0[4], ad1[4];
#pragma unroll
    for (int q = 0; q < 4; ++q) {
        as0[q] = atts[q * 32 + col];
        as1[q] = atts[q * 32 + 16 + col];
        ad0[q] = attd[q * 32 + col];
        ad1[q] = attd[q * 32 + 16 + col];
    }
#pragma unroll
    for (int r = 0; r < 4; ++r) {
        int node = row0 + w * 16 + kq * 4 + r;
        float ps[4], pd[4];
#pragma unroll
        for (int q = 0; q < 4; ++q) {
            float d0 = acc[2 * q][r], d1 = acc[2 * q + 1][r];
            ps[q] = d0 * as0[q] + d1 * as1[q];
            pd[q] = d0 * ad0[q] + d1 * ad1[q];
        }
#pragma unroll
        for (int off = 1; off < 16; off <<= 1) {
#pragma unroll
            for (int q = 0; q < 4; ++q) {
                ps[q] += __shfl_xor(ps[q], off);
                pd[q] += __shfl_xor(pd[q], off);
            }
        }
        if (node < NN) {
#pragma unroll
            for (int ct = 0; ct < 8; ++ct)
                hb[(size_t)node * 128 + ct * 16 + col] = (u16)bf16r(acc[ct][r]);
            if (col < 4) {
                float vs = col == 0 ? ps[0] : col == 1 ? ps[1] : col == 2 ? ps[2] : ps[3];
                float vd = col == 0 ? pd[0] : col == 1 ? pd[1] : col == 2 ? pd[2] : pd[3];
                a_src[node * 4 + col] = vs;
                a_dst[node * 4 + col] = vd;
            }
        }
    }
}

// ---------------- fused: gemm1 (every 5th block) | atomic-free scatter -------
__global__ __launch_bounds__(256) void k_sg(
    const float* __restrict__ x,
    const bf16x8* __restrict__ wpH, const bf16x8* __restrict__ wpL,
    const float* __restrict__ atts, const float* __restrict__ attd,
    u16* __restrict__ hb, float* __restrict__ a_src, float* __restrict__ a_dst,
    const int* __restrict__ src, const int* __restrict__ dst,
    const int* __restrict__ occ, const int* __restrict__ row_ptr,
    int* __restrict__ src_sorted) {
    __shared__ __align__(16) float xs[64][132];
    const int idx = blockIdx.x;
    const int g5 = idx / 5;
    const bool is_gemm = (idx % 5 == 0) && (g5 < GEMM_GRID);
    if (!is_gemm) {
        int sb = idx - (GEMM_GRID < (idx + 4) / 5 ? GEMM_GRID : (idx + 4) / 5);
        int e = sb * 256 + threadIdx.x;
        if (e < NE) {
            int d = dst[e];
            src_sorted[row_ptr[d] + occ[e]] = src[e];
        }
        return;
    }
    const int t = threadIdx.x;
    const int row0 = g5 * 64;
#pragma unroll
    for (int i = 0; i < 8; ++i) {
        int f4 = t + 256 * i;
        int r = f4 >> 5, c4 = f4 & 31;
        int node = row0 + r;
        float4 v = make_float4(0.f, 0.f, 0.f, 0.f);
        if (node < NN) v = *(const float4*)(x + (size_t)node * 128 + c4 * 4);
        *(float4*)&xs[r][c4 * 4] = v;
    }
    __syncthreads();
    const int lane = t & 63;
    const int w = t >> 6;
    const int col = lane & 15, kq = lane >> 4;
    f32x4 acc[8];
#pragma unroll
    for (int ct = 0; ct < 8; ++ct) acc[ct] = (f32x4){0.f, 0.f, 0.f, 0.f};
#pragma unroll
    for (int kc = 0; kc < 4; ++kc) {
        const float* ap = &xs[w * 16 + col][kc * 32 + kq * 8];
        float a[8];
        *(float4*)&a[0] = *(const float4*)ap;
        *(float4*)&a[4] = *(const float4*)(ap + 4);
        u32 hh[4], ll[4];
        split_pack8(a, hh, ll);
        bf16x8 ah = __builtin_bit_cast(bf16x8, (u32x4){hh[0], hh[1], hh[2], hh[3]});
        bf16x8 al = __builtin_bit_cast(bf16x8, (u32x4){ll[0], ll[1], ll[2], ll[3]});
#pragma unroll
        for (int ct = 0; ct < 8; ++ct) {
            bf16x8 bh = wpH[(kc * 8 + ct) * 64 + lane];
            bf16x8 bl = wpL[(kc * 8 + ct) * 64 + lane];
            acc[ct] = __builtin_amdgcn_mfma_f32_16x16x32_bf16(ah, bh, acc[ct], 0, 0, 0);
            acc[ct] = __builtin_amdgcn_mfma_f32_16x16x32_bf16(al, bh, acc[ct], 0, 0, 0);
            acc[ct] = __builtin_amdgcn_mfma_f32_16x16x32_bf16(ah, bl, acc[ct], 0, 0, 0);
        }
    }
    gemm_epilogue(acc, row0, w, col, kq, atts, attd, hb, a_src, a_dst);
}

// ---------------- GEMM layer 2: bf16 input (exact A), split B ----------------
__global__ __launch_bounds__(256) void k_gemm2(
    const u32* __restrict__ xb,   // [NN][64] bf16 pairs (ch 2j low, 2j+1 high)
    const bf16x8* __restrict__ wpH, const bf16x8* __restrict__ wpL,
    const float* __restrict__ atts, const float* __restrict__ attd,
    u16* __restrict__ hb, float* __restrict__ a_src, float* __restrict__ a_dst) {
    __shared__ __align__(16) u32 xs[64][68];
    const int t = threadIdx.x;
    const int row0 = blockIdx.x * 64;
#pragma unroll
    for (int i = 0; i < 16; ++i) {
        int idx = t + 256 * i;
        int r = idx >> 6, c = idx & 63;
        int node = row0 + r;
        xs[r][c] = (node < NN) ? xb[node * 64 + c] : 0u;
    }
    __syncthreads();
    const int lane = t & 63;
    const int w = t >> 6;
    const int col = lane & 15, kq = lane >> 4;
    f32x4 acc[8];
#pragma unroll
    for (int ct = 0; ct < 8; ++ct) acc[ct] = (f32x4){0.f, 0.f, 0.f, 0.f};
#pragma unroll
    for (int kc = 0; kc < 4; ++kc) {
        const u32* ap = &xs[w * 16 + col][kc * 16 + kq * 4];
        int4 aw = *(const int4*)ap;
        bf16x8 a = __builtin_bit_cast(bf16x8, aw);
#pragma unroll
        for (int ct = 0; ct < 8; ++ct) {
            bf16x8 bh = wpH[(kc * 8 + ct) * 64 + lane];
            bf16x8 bl = wpL[(kc * 8 + ct) * 64 + lane];
            acc[ct] = __builtin_amdgcn_mfma_f32_16x16x32_bf16(a, bh, acc[ct], 0, 0, 0);
            acc[ct] = __builtin_amdgcn_mfma_f32_16x16x32_bf16(a, bl, acc[ct], 0, 0, 0);
        }
    }
    gemm_epilogue(acc, row0, w, col, kq, atts, attd, hb, a_src, a_dst);
}

// ---------------- aggregation: static-max softmax, bf16 gathers ----------------
#define AGG_BODY(GUARD)                                                        \
    for (int u = 0; u < 16; ++u) {                                             \
        GUARD                                                                  \
        float exu = __shfl(ex, hbase | u);                                     \
        int su = __builtin_amdgcn_readlane(sv, u);                             \
        u32 wv = hb[su * 64 + lane];                                           \
        float h0 = __uint_as_float(wv << 16);                                  \
        float h1 = __uint_as_float(wv & 0xFFFF0000u);                          \
        if (u & 1) { a0b = fmaf(exu, h0, a0b); a1b = fmaf(exu, h1, a1b); }     \
        else       { a0a = fmaf(exu, h0, a0a); a1a = fmaf(exu, h1, a1a); }     \
    }

__global__ __launch_bounds__(256) void k_agg(
    const u32* __restrict__ hb,   // [NN][64] bf16 pairs
    const float* __restrict__ a_src, const float* __restrict__ a_dst,
    const int* __restrict__ row_ptr, const int* __restrict__ src_sorted,
    const float* __restrict__ bias,
    u32* __restrict__ x1b, float* __restrict__ outp, int layer) {
    const int lane = threadIdx.x & 63;
    const int node = blockIdx.x * 4 + (threadIdx.x >> 6);
    if (node >= NN) return;
    const int q = lane >> 4;
    const int es = lane & 15;
    const int hbase = lane & 48;
    const int e0 = row_ptr[node], e1 = row_ptr[node + 1];
    const float advh = a_dst[node * 4 + q];
    float den = 0.f, a0a = 0.f, a0b = 0.f, a1a = 0.f, a1b = 0.f;
    for (int ec = e0; ec < e1; ec += 16) {
        int cnt = e1 - ec;
        cnt = cnt < 16 ? cnt : 16;
        int eidx = ec + es;
        int emax = e1 - 1;
        if (eidx > emax) eidx = emax;
        int sv = src_sorted[eidx];
        float av = a_src[sv * 4 + q];
        float lk = av + advh;
        lk = lk > 0.f ? lk : 0.2f * lk;
        float ex = (es < cnt) ? __expf(lk - 8.f) : 0.f;
        den += ex;
        if (cnt == 16) {
#pragma unroll
            AGG_BODY(;)
        } else {
#pragma unroll
            AGG_BODY(if (u >= cnt) break;)
        }
    }
    float a0 = a0a + a0b, a1 = a1a + a1b;
#pragma unroll
    for (int m = 1; m < 16; m <<= 1) den += __shfl_xor(den, m);
    float inv = den > 0.f ? 1.f / den : 0.f;
    int c0 = lane * 2;
    float r0 = fmaxf(fmaf(a0, inv, bias[c0]), 0.f);
    float r1 = fmaxf(fmaf(a1, inv, bias[c0 + 1]), 0.f);
    if (layer == 1) {
        x1b[node * 64 + lane] = bf16r(r0) | (bf16r(r1) << 16);
    } else {
        u32 w1 = x1b[node * 64 + lane];
        float4 o;
        o.x = __uint_as_float(w1 << 16);          // x1[2l]
        o.y = r0;                                  // x2[2l]
        o.z = __uint_as_float(w1 & 0xFFFF0000u);  // x1[2l+1]
        o.w = r1;                                  // x2[2l+1]
        *(float4*)(outp + (size_t)node * 256 + lane * 4) = o;
    }
}

// ---------------- launch ----------------

extern "C" void kernel_launch(void* const* d_in, const int* in_sizes, int n_in,
                              void* d_out, int out_size, void* d_ws, size_t ws_size,
                              hipStream_t stream) {
    const float* x   = (const float*)d_in[0];
    const int*   ei  = (const int*)d_in[1];
    const float* W1  = (const float*)d_in[2];
    const float* as1 = (const float*)d_in[3];
    const float* ad1 = (const float*)d_in[4];
    const float* b1  = (const float*)d_in[5];
    const float* W2  = (const float*)d_in[6];
    const float* as2 = (const float*)d_in[7];
    const float* ad2 = (const float*)d_in[8];
    const float* b2  = (const float*)d_in[9];
    float* out = (float*)d_out;
    const int* src = ei;
    const int* dst = ei + NE;

    char* w = (char*)d_ws;
    size_t off = 0;
    auto alloc = [&](size_t bytes) -> void* {
        void* p = w + off;
        off = (off + bytes + 255) & ~((size_t)255);
        return p;
    };
    u16* hb         = (u16*)alloc((size_t)NN * 128 * 2);   // h as bf16
    u32* x1b        = (u32*)alloc((size_t)NN * 64 * 4);    // x1 as bf16 pairs
    float* a_src    = (float*)alloc((size_t)NN * 4 * 4);
    float* a_dst    = (float*)alloc((size_t)NN * 4 * 4);
    int* counts     = (int*)alloc((size_t)NN * 4);
    int* row_ptr    = (int*)alloc((size_t)(NN + 1) * 4);
    int* csum       = (int*)alloc(4096);
    int* occ        = (int*)alloc((size_t)NE * 4);
    int* src_sorted = (int*)alloc((size_t)NE * 4);
    bf16x8* wpH1    = (bf16x8*)alloc(2048 * 16);
    bf16x8* wpL1    = (bf16x8*)alloc(2048 * 16);
    bf16x8* wpH2    = (bf16x8*)alloc(2048 * 16);
    bf16x8* wpL2    = (bf16x8*)alloc(2048 * 16);

    const int nch = (NN + SCAN_CH - 1) / SCAN_CH;  // 98

    (void)hipMemsetAsync(counts, 0, (size_t)NN * 4, stream);
    // wpack(W1) | wpack(W2) | hist + occurrence index
    k_wh<<<WH_GRID, 256, 0, stream>>>(W1, wpH1, wpL1, W2, wpH2, wpL2,
                                      dst, counts, occ);
    k_scan1<<<nch, 256, 0, stream>>>(counts, csum);
    k_scan2<<<1, 64, 0, stream>>>(csum, nch);
    k_scan3<<<nch, 256, 0, stream>>>(counts, csum, row_ptr);
    // gemm1 (interleaved every 5th block) | atomic-free scatter
    k_sg<<<SG_GRID, 256, 0, stream>>>(x, wpH1, wpL1, as1, ad1, hb, a_src, a_dst,
                                      src, dst, occ, row_ptr, src_sorted);

    const int agg_grid = (NN + 3) / 4;
    k_agg<<<agg_grid, 256, 0, stream>>>((const u32*)hb, a_src, a_dst, row_ptr,
                                        src_sorted, b1, x1b, out, 1);
    k_gemm2<<<(NN + 63) / 64, 256, 0, stream>>>(x1b, wpH2, wpL2, as2, ad2,
                                                hb, a_src, a_dst);
    k_agg<<<agg_grid, 256, 0, stream>>>((const u32*)hb, a_src, a_dst, row_ptr,
                                        src_sorted, b2, x1b, out, 2);
}

// Round 7
// 367.371 us; speedup vs baseline: 3.2988x; 1.0259x over previous
//
#include <hip/hip_runtime.h>

#define NN 100000
#define NE 1600000
#define SCAN_CH 1024
#define GEMM_GRID 1563            // ceil(NN/64)
#define SCAT_GRID 6250            // NE/256
#define SG_GRID (GEMM_GRID + SCAT_GRID)
#define WH_GRID (16 + SCAT_GRID)  // wpack x2 + hist

typedef short bf16x8 __attribute__((ext_vector_type(8)));
typedef float f32x4 __attribute__((ext_vector_type(4)));
typedef unsigned int u32;
typedef u32 u32x4 __attribute__((ext_vector_type(4)));
typedef unsigned short u16;

__device__ inline u32 bf16r(float x) {  // RTNE bf16, returns low-16 bits
    u32 u = __float_as_uint(x);
    return (u + 0x7FFFu + ((u >> 16) & 1u)) >> 16;
}

// ---------------- split-bf16 helpers ----------------
__device__ inline void split_pack8(const float a[8], u32 hh[4], u32 ll[4]) {
#pragma unroll
    for (int j = 0; j < 4; ++j) {
        u32 u0 = __float_as_uint(a[2 * j]);
        u32 u1 = __float_as_uint(a[2 * j + 1]);
        float l0 = a[2 * j] - __uint_as_float(u0 & 0xFFFF0000u);
        float l1 = a[2 * j + 1] - __uint_as_float(u1 & 0xFFFF0000u);
        hh[j] = (u0 >> 16) | (u1 & 0xFFFF0000u);
        ll[j] = (__float_as_uint(l0) >> 16) | (__float_as_uint(l1) & 0xFFFF0000u);
    }
}

__device__ inline void wpack_body(int idx, const float* __restrict__ W,
                                  bf16x8* __restrict__ wpH, bf16x8* __restrict__ wpL) {
    if (idx >= 2048) return;
    int lane = idx & 63, tile = idx >> 6;
    int kc = tile >> 3, ct = tile & 7;
    int col = lane & 15, kq = lane >> 4;
    int kbase = kc * 32 + kq * 8;
    float a[8];
#pragma unroll
    for (int i = 0; i < 8; ++i)
        a[i] = W[(size_t)(kbase + i) * 128 + ct * 16 + col];
    u32 hh[4], ll[4];
    split_pack8(a, hh, ll);
    wpH[tile * 64 + lane] = __builtin_bit_cast(bf16x8, (u32x4){hh[0], hh[1], hh[2], hh[3]});
    wpL[tile * 64 + lane] = __builtin_bit_cast(bf16x8, (u32x4){ll[0], ll[1], ll[2], ll[3]});
}

// ---------------- fused: wpack(W1) | wpack(W2) | hist+occ ----------------
__global__ __launch_bounds__(256) void k_wh(
    const float* __restrict__ W1, bf16x8* __restrict__ wpH1, bf16x8* __restrict__ wpL1,
    const float* __restrict__ W2, bf16x8* __restrict__ wpH2, bf16x8* __restrict__ wpL2,
    const int* __restrict__ dst, int* __restrict__ counts, int* __restrict__ occ) {
    int b = blockIdx.x;
    if (b < 8) {
        wpack_body(b * 256 + threadIdx.x, W1, wpH1, wpL1);
    } else if (b < 16) {
        wpack_body((b - 8) * 256 + threadIdx.x, W2, wpH2, wpL2);
    } else {
        int e = (b - 16) * 256 + threadIdx.x;
        if (e < NE) occ[e] = atomicAdd(&counts[dst[e]], 1);
    }
}

// ---------------- scans ----------------
__global__ __launch_bounds__(256) void k_scan1(const int* __restrict__ counts,
                                               int* __restrict__ csum) {
    __shared__ int sd[256];
    int t = threadIdx.x;
    int base = blockIdx.x * SCAN_CH + t * 4;
    int s = 0;
#pragma unroll
    for (int u = 0; u < 4; ++u) {
        int i = base + u;
        if (i < NN) s += counts[i];
    }
    sd[t] = s;
    __syncthreads();
    for (int off = 128; off > 0; off >>= 1) {
        if (t < off) sd[t] += sd[t + off];
        __syncthreads();
    }
    if (t == 0) csum[blockIdx.x] = sd[0];
}

__global__ __launch_bounds__(64) void k_scan2(int* csum, int nch) {
    if (threadIdx.x == 0 && blockIdx.x == 0) {
        int run = 0;
        for (int i = 0; i < nch; ++i) {
            int v = csum[i];
            csum[i] = run;
            run += v;
        }
    }
}

__global__ __launch_bounds__(256) void k_scan3(const int* __restrict__ counts,
                                               const int* __restrict__ csum,
                                               int* __restrict__ row_ptr) {
    __shared__ int sd[256];
    int t = threadIdx.x, b = blockIdx.x;
    int base = b * SCAN_CH + t * 4;
    int v[4];
    int s = 0;
#pragma unroll
    for (int u = 0; u < 4; ++u) {
        int i = base + u;
        v[u] = (i < NN) ? counts[i] : 0;
        s += v[u];
    }
    sd[t] = s;
    __syncthreads();
    for (int off = 1; off < 256; off <<= 1) {
        int x = (t >= off) ? sd[t - off] : 0;
        __syncthreads();
        sd[t] += x;
        __syncthreads();
    }
    int excl = (t == 0) ? 0 : sd[t - 1];
    int run = csum[b] + excl;
#pragma unroll
    for (int u = 0; u < 4; ++u) {
        int i = base + u;
        if (i < NN) row_ptr[i] = run;
        run += v[u];
    }
    if (b == 0 && t == 0) row_ptr[NN] = NE;
}

// shared GEMM epilogue: h (bf16) + attention logits
__device__ inline void gemm_epilogue(f32x4 acc[8], int row0, int w, int col, int kq,
                                     const float* __restrict__ atts,
                                     const float* __restrict__ attd,
                                     u16* __restrict__ hb,
                                     float* __restrict__ a_src,
                                     float* __restrict__ a_dst) {
    float as0[4], as1[4], ad0[4], ad1[4];
#pragma unroll
    for (int q = 0; q < 4; ++q) {
        as0[q] = atts[q * 32 + col];
        as1[q] = atts[q * 32 + 16 + col];
        ad0[q] = attd[q * 32 + col];
        ad1[q] = attd[q * 32 + 16 + col];
    }
#pragma unroll
    for (int r = 0; r < 4; ++r) {
        int node = row0 + w * 16 + kq * 4 + r;
        float ps[4], pd[4];
#pragma unroll
        for (int q = 0; q < 4; ++q) {
            float d0 = acc[2 * q][r], d1 = acc[2 * q + 1][r];
            ps[q] = d0 * as0[q] + d1 * as1[q];
            pd[q] = d0 * ad0[q] + d1 * ad1[q];
        }
#pragma unroll
        for (int off = 1; off < 16; off <<= 1) {
#pragma unroll
            for (int q = 0; q < 4; ++q) {
                ps[q] += __shfl_xor(ps[q], off);
                pd[q] += __shfl_xor(pd[q], off);
            }
        }
        if (node < NN) {
#pragma unroll
            for (int ct = 0; ct < 8; ++ct)
                hb[(size_t)node * 128 + ct * 16 + col] = (u16)bf16r(acc[ct][r]);
            if (col < 4) {
                float vs = col == 0 ? ps[0] : col == 1 ? ps[1] : col == 2 ? ps[2] : ps[3];
                float vd = col == 0 ? pd[0] : col == 1 ? pd[1] : col == 2 ? pd[2] : pd[3];
                a_src[node * 4 + col] = vs;
                a_dst[node * 4 + col] = vd;
            }
        }
    }
}

// ---------------- fused: gemm1 (every 5th block, LDS-free) | scatter --------
__global__ __launch_bounds__(256) void k_sg(
    const float* __restrict__ x,
    const bf16x8* __restrict__ wpH, const bf16x8* __restrict__ wpL,
    const float* __restrict__ atts, const float* __restrict__ attd,
    u16* __restrict__ hb, float* __restrict__ a_src, float* __restrict__ a_dst,
    const int* __restrict__ src, const int* __restrict__ dst,
    const int* __restrict__ occ, const int* __restrict__ row_ptr,
    int* __restrict__ src_sorted) {
    const int idx = blockIdx.x;
    const int g5 = idx / 5;
    const bool is_gemm = (idx % 5 == 0) && (g5 < GEMM_GRID);
    if (!is_gemm) {
        int nslots = (idx + 4) / 5;
        if (nslots > GEMM_GRID) nslots = GEMM_GRID;
        int sb = idx - nslots;
        int e = sb * 256 + threadIdx.x;
        if (e < NE) {
            int d = dst[e];
            src_sorted[row_ptr[d] + occ[e]] = src[e];
        }
        return;
    }
    const int t = threadIdx.x;
    const int row0 = g5 * 64;
    const int lane = t & 63;
    const int w = t >> 6;
    const int col = lane & 15, kq = lane >> 4;
    // A-frag row for this lane; clamp (MFMA rows are independent, stores guarded)
    int node_a = row0 + w * 16 + col;
    if (node_a > NN - 1) node_a = NN - 1;
    const float* xrow = x + (size_t)node_a * 128 + kq * 8;
    // load all 32 A elements up front (max MLP), then split per kc
    float a[32];
#pragma unroll
    for (int kc = 0; kc < 4; ++kc) {
        *(float4*)&a[kc * 8 + 0] = *(const float4*)(xrow + kc * 32);
        *(float4*)&a[kc * 8 + 4] = *(const float4*)(xrow + kc * 32 + 4);
    }
    f32x4 acc[8];
#pragma unroll
    for (int ct = 0; ct < 8; ++ct) acc[ct] = (f32x4){0.f, 0.f, 0.f, 0.f};
#pragma unroll
    for (int kc = 0; kc < 4; ++kc) {
        u32 hh[4], ll[4];
        split_pack8(&a[kc * 8], hh, ll);
        bf16x8 ah = __builtin_bit_cast(bf16x8, (u32x4){hh[0], hh[1], hh[2], hh[3]});
        bf16x8 al = __builtin_bit_cast(bf16x8, (u32x4){ll[0], ll[1], ll[2], ll[3]});
#pragma unroll
        for (int ct = 0; ct < 8; ++ct) {
            bf16x8 bh = wpH[(kc * 8 + ct) * 64 + lane];
            bf16x8 bl = wpL[(kc * 8 + ct) * 64 + lane];
            acc[ct] = __builtin_amdgcn_mfma_f32_16x16x32_bf16(ah, bh, acc[ct], 0, 0, 0);
            acc[ct] = __builtin_amdgcn_mfma_f32_16x16x32_bf16(al, bh, acc[ct], 0, 0, 0);
            acc[ct] = __builtin_amdgcn_mfma_f32_16x16x32_bf16(ah, bl, acc[ct], 0, 0, 0);
        }
    }
    gemm_epilogue(acc, row0, w, col, kq, atts, attd, hb, a_src, a_dst);
}

// ---------------- GEMM layer 2: bf16 input (exact A), LDS-free --------------
__global__ __launch_bounds__(256) void k_gemm2(
    const u32* __restrict__ xb,   // [NN][64] bf16 pairs (ch 2j low, 2j+1 high)
    const bf16x8* __restrict__ wpH, const bf16x8* __restrict__ wpL,
    const float* __restrict__ atts, const float* __restrict__ attd,
    u16* __restrict__ hb, float* __restrict__ a_src, float* __restrict__ a_dst) {
    const int t = threadIdx.x;
    const int row0 = blockIdx.x * 64;
    const int lane = t & 63;
    const int w = t >> 6;
    const int col = lane & 15, kq = lane >> 4;
    int node_a = row0 + w * 16 + col;
    if (node_a > NN - 1) node_a = NN - 1;
    const u32* xrow = xb + (size_t)node_a * 64 + kq * 4;
    int4 aw[4];
#pragma unroll
    for (int kc = 0; kc < 4; ++kc) aw[kc] = *(const int4*)(xrow + kc * 16);
    f32x4 acc[8];
#pragma unroll
    for (int ct = 0; ct < 8; ++ct) acc[ct] = (f32x4){0.f, 0.f, 0.f, 0.f};
#pragma unroll
    for (int kc = 0; kc < 4; ++kc) {
        bf16x8 a = __builtin_bit_cast(bf16x8, aw[kc]);
#pragma unroll
        for (int ct = 0; ct < 8; ++ct) {
            bf16x8 bh = wpH[(kc * 8 + ct) * 64 + lane];
            bf16x8 bl = wpL[(kc * 8 + ct) * 64 + lane];
            acc[ct] = __builtin_amdgcn_mfma_f32_16x16x32_bf16(a, bh, acc[ct], 0, 0, 0);
            acc[ct] = __builtin_amdgcn_mfma_f32_16x16x32_bf16(a, bl, acc[ct], 0, 0, 0);
        }
    }
    gemm_epilogue(acc, row0, w, col, kq, atts, attd, hb, a_src, a_dst);
}

// ---------------- aggregation: static-max softmax, chunk prefetch ----------
#define AGG_BODY(GUARD)                                                        \
    for (int u = 0; u < 16; ++u) {                                             \
        GUARD                                                                  \
        float exu = __shfl(ex, hbase | u);                                     \
        int su = __builtin_amdgcn_readlane(sv, u);                             \
        const u32* p = hb + ((size_t)su << 6);                                 \
        u32 wv = p[lane];                                                      \
        float h0 = __uint_as_float(wv << 16);                                  \
        float h1 = __uint_as_float(wv & 0xFFFF0000u);                          \
        if (u & 1) { a0b = fmaf(exu, h0, a0b); a1b = fmaf(exu, h1, a1b); }     \
        else       { a0a = fmaf(exu, h0, a0a); a1a = fmaf(exu, h1, a1a); }     \
    }

__global__ __launch_bounds__(256) void k_agg(
    const u32* __restrict__ hb,   // [NN][64] bf16 pairs
    const float* __restrict__ a_src, const float* __restrict__ a_dst,
    const int* __restrict__ row_ptr, const int* __restrict__ src_sorted,
    const float* __restrict__ bias,
    u32* __restrict__ x1b, float* __restrict__ outp, int layer) {
    const int lane = threadIdx.x & 63;
    const int node = blockIdx.x * 4 + (threadIdx.x >> 6);
    if (node >= NN) return;
    const int q = lane >> 4;
    const int es = lane & 15;
    const int hbase = lane & 48;
    const int e0 = row_ptr[node], e1 = row_ptr[node + 1];
    const int emax = e1 - 1;
    const float advh = a_dst[node * 4 + q];
    float den = 0.f, a0a = 0.f, a0b = 0.f, a1a = 0.f, a1b = 0.f;
    // prefetch chunk 0
    int eidx = e0 + es;
    if (eidx > emax) eidx = emax;
    int sv = src_sorted[eidx];
    float av = a_src[sv * 4 + q];
    for (int ec = e0; ec < e1; ec += 16) {
        int cnt = e1 - ec;
        cnt = cnt < 16 ? cnt : 16;
        // prefetch next chunk (clamped; harmless dup loads on last chunk)
        int eidxn = ec + 16 + es;
        if (eidxn > emax) eidxn = emax;
        int svn = src_sorted[eidxn];
        float avn = a_src[svn * 4 + q];
        // current chunk
        float lk = av + advh;
        lk = lk > 0.f ? lk : 0.2f * lk;
        float ex = (es < cnt) ? __expf(lk - 8.f) : 0.f;
        den += ex;
        if (cnt == 16) {
#pragma unroll
            AGG_BODY(;)
        } else {
#pragma unroll
            AGG_BODY(if (u >= cnt) break;)
        }
        sv = svn;
        av = avn;
    }
    float a0 = a0a + a0b, a1 = a1a + a1b;
#pragma unroll
    for (int m = 1; m < 16; m <<= 1) den += __shfl_xor(den, m);
    float inv = den > 0.f ? 1.f / den : 0.f;
    int c0 = lane * 2;
    float r0 = fmaxf(fmaf(a0, inv, bias[c0]), 0.f);
    float r1 = fmaxf(fmaf(a1, inv, bias[c0 + 1]), 0.f);
    if (layer == 1) {
        x1b[node * 64 + lane] = bf16r(r0) | (bf16r(r1) << 16);
    } else {
        u32 w1 = x1b[node * 64 + lane];
        float4 o;
        o.x = __uint_as_float(w1 << 16);          // x1[2l]
        o.y = r0;                                  // x2[2l]
        o.z = __uint_as_float(w1 & 0xFFFF0000u);  // x1[2l+1]
        o.w = r1;                                  // x2[2l+1]
        *(float4*)(outp + (size_t)node * 256 + lane * 4) = o;
    }
}

// ---------------- launch ----------------

extern "C" void kernel_launch(void* const* d_in, const int* in_sizes, int n_in,
                              void* d_out, int out_size, void* d_ws, size_t ws_size,
                              hipStream_t stream) {
    const float* x   = (const float*)d_in[0];
    const int*   ei  = (const int*)d_in[1];
    const float* W1  = (const float*)d_in[2];
    const float* as1 = (const float*)d_in[3];
    const float* ad1 = (const float*)d_in[4];
    const float* b1  = (const float*)d_in[5];
    const float* W2  = (const float*)d_in[6];
    const float* as2 = (const float*)d_in[7];
    const float* ad2 = (const float*)d_in[8];
    const float* b2  = (const float*)d_in[9];
    float* out = (float*)d_out;
    const int* src = ei;
    const int* dst = ei + NE;

    char* w = (char*)d_ws;
    size_t off = 0;
    auto alloc = [&](size_t bytes) -> void* {
        void* p = w + off;
        off = (off + bytes + 255) & ~((size_t)255);
        return p;
    };
    u16* hb         = (u16*)alloc((size_t)NN * 128 * 2);   // h as bf16
    u32* x1b        = (u32*)alloc((size_t)NN * 64 * 4);    // x1 as bf16 pairs
    float* a_src    = (float*)alloc((size_t)NN * 4 * 4);
    float* a_dst    = (float*)alloc((size_t)NN * 4 * 4);
    int* counts     = (int*)alloc((size_t)NN * 4);
    int* row_ptr    = (int*)alloc((size_t)(NN + 1) * 4);
    int* csum       = (int*)alloc(4096);
    int* occ        = (int*)alloc((size_t)NE * 4);
    int* src_sorted = (int*)alloc((size_t)NE * 4);
    bf16x8* wpH1    = (bf16x8*)alloc(2048 * 16);
    bf16x8* wpL1    = (bf16x8*)alloc(2048 * 16);
    bf16x8* wpH2    = (bf16x8*)alloc(2048 * 16);
    bf16x8* wpL2    = (bf16x8*)alloc(2048 * 16);

    const int nch = (NN + SCAN_CH - 1) / SCAN_CH;  // 98

    (void)hipMemsetAsync(counts, 0, (size_t)NN * 4, stream);
    // wpack(W1) | wpack(W2) | hist + occurrence index
    k_wh<<<WH_GRID, 256, 0, stream>>>(W1, wpH1, wpL1, W2, wpH2, wpL2,
                                      dst, counts, occ);
    k_scan1<<<nch, 256, 0, stream>>>(counts, csum);
    k_scan2<<<1, 64, 0, stream>>>(csum, nch);
    k_scan3<<<nch, 256, 0, stream>>>(counts, csum, row_ptr);
    // gemm1 (interleaved every 5th block) | atomic-free scatter
    k_sg<<<SG_GRID, 256, 0, stream>>>(x, wpH1, wpL1, as1, ad1, hb, a_src, a_dst,
                                      src, dst, occ, row_ptr, src_sorted);

    const int agg_grid = (NN + 3) / 4;
    k_agg<<<agg_grid, 256, 0, stream>>>((const u32*)hb, a_src, a_dst, row_ptr,
                                        src_sorted, b1, x1b, out, 1);
    k_gemm2<<<(NN + 63) / 64, 256, 0, stream>>>(x1b, wpH2, wpL2, as2, ad2,
                                                hb, a_src, a_dst);
    k_agg<<<agg_grid, 256, 0, stream>>>((const u32*)hb, a_src, a_dst, row_ptr,
                                        src_sorted, b2, x1b, out, 2);
}

// Round 8
// 323.230 us; speedup vs baseline: 3.7493x; 1.1366x over previous
//
#include <hip/hip_runtime.h>

#define NN 100000
#define NE 1600000
#define SCAN_CH 1024
#define GEMM_GRID 1563            // ceil(NN/64)
#define SCAT_GRID 6250            // NE/256
#define SG_GRID (GEMM_GRID + SCAT_GRID)
#define WH_GRID (16 + SCAT_GRID)  // wpack x2 + hist

typedef short bf16x8 __attribute__((ext_vector_type(8)));
typedef float f32x4 __attribute__((ext_vector_type(4)));
typedef unsigned int u32;
typedef u32 u32x4 __attribute__((ext_vector_type(4)));
typedef unsigned short u16;

__device__ inline u32 bf16r(float x) {  // RTNE bf16, returns low-16 bits
    u32 u = __float_as_uint(x);
    return (u + 0x7FFFu + ((u >> 16) & 1u)) >> 16;
}

// ---------------- split-bf16 helpers ----------------
__device__ inline void split_pack8(const float a[8], u32 hh[4], u32 ll[4]) {
#pragma unroll
    for (int j = 0; j < 4; ++j) {
        u32 u0 = __float_as_uint(a[2 * j]);
        u32 u1 = __float_as_uint(a[2 * j + 1]);
        float l0 = a[2 * j] - __uint_as_float(u0 & 0xFFFF0000u);
        float l1 = a[2 * j + 1] - __uint_as_float(u1 & 0xFFFF0000u);
        hh[j] = (u0 >> 16) | (u1 & 0xFFFF0000u);
        ll[j] = (__float_as_uint(l0) >> 16) | (__float_as_uint(l1) & 0xFFFF0000u);
    }
}

__device__ inline void wpack_body(int idx, const float* __restrict__ W,
                                  bf16x8* __restrict__ wpH, bf16x8* __restrict__ wpL) {
    if (idx >= 2048) return;
    int lane = idx & 63, tile = idx >> 6;
    int kc = tile >> 3, ct = tile & 7;
    int col = lane & 15, kq = lane >> 4;
    int kbase = kc * 32 + kq * 8;
    float a[8];
#pragma unroll
    for (int i = 0; i < 8; ++i)
        a[i] = W[(size_t)(kbase + i) * 128 + ct * 16 + col];
    u32 hh[4], ll[4];
    split_pack8(a, hh, ll);
    wpH[tile * 64 + lane] = __builtin_bit_cast(bf16x8, (u32x4){hh[0], hh[1], hh[2], hh[3]});
    wpL[tile * 64 + lane] = __builtin_bit_cast(bf16x8, (u32x4){ll[0], ll[1], ll[2], ll[3]});
}

// ---------------- fused: wpack(W1) | wpack(W2) | hist+occ ----------------
__global__ __launch_bounds__(256) void k_wh(
    const float* __restrict__ W1, bf16x8* __restrict__ wpH1, bf16x8* __restrict__ wpL1,
    const float* __restrict__ W2, bf16x8* __restrict__ wpH2, bf16x8* __restrict__ wpL2,
    const int* __restrict__ dst, int* __restrict__ counts, int* __restrict__ occ) {
    int b = blockIdx.x;
    if (b < 8) {
        wpack_body(b * 256 + threadIdx.x, W1, wpH1, wpL1);
    } else if (b < 16) {
        wpack_body((b - 8) * 256 + threadIdx.x, W2, wpH2, wpL2);
    } else {
        int e = (b - 16) * 256 + threadIdx.x;
        if (e < NE) occ[e] = atomicAdd(&counts[dst[e]], 1);
    }
}

// ---------------- scans ----------------
__global__ __launch_bounds__(256) void k_scan1(const int* __restrict__ counts,
                                               int* __restrict__ csum) {
    __shared__ int sd[256];
    int t = threadIdx.x;
    int base = blockIdx.x * SCAN_CH + t * 4;
    int s = 0;
#pragma unroll
    for (int u = 0; u < 4; ++u) {
        int i = base + u;
        if (i < NN) s += counts[i];
    }
    sd[t] = s;
    __syncthreads();
    for (int off = 128; off > 0; off >>= 1) {
        if (t < off) sd[t] += sd[t + off];
        __syncthreads();
    }
    if (t == 0) csum[blockIdx.x] = sd[0];
}

__global__ __launch_bounds__(64) void k_scan2(int* csum, int nch) {
    if (threadIdx.x == 0 && blockIdx.x == 0) {
        int run = 0;
        for (int i = 0; i < nch; ++i) {
            int v = csum[i];
            csum[i] = run;
            run += v;
        }
    }
}

__global__ __launch_bounds__(256) void k_scan3(const int* __restrict__ counts,
                                               const int* __restrict__ csum,
                                               int* __restrict__ row_ptr) {
    __shared__ int sd[256];
    int t = threadIdx.x, b = blockIdx.x;
    int base = b * SCAN_CH + t * 4;
    int v[4];
    int s = 0;
#pragma unroll
    for (int u = 0; u < 4; ++u) {
        int i = base + u;
        v[u] = (i < NN) ? counts[i] : 0;
        s += v[u];
    }
    sd[t] = s;
    __syncthreads();
    for (int off = 1; off < 256; off <<= 1) {
        int x = (t >= off) ? sd[t - off] : 0;
        __syncthreads();
        sd[t] += x;
        __syncthreads();
    }
    int excl = (t == 0) ? 0 : sd[t - 1];
    int run = csum[b] + excl;
#pragma unroll
    for (int u = 0; u < 4; ++u) {
        int i = base + u;
        if (i < NN) row_ptr[i] = run;
        run += v[u];
    }
    if (b == 0 && t == 0) row_ptr[NN] = NE;
}

// shared GEMM epilogue: h (bf16) + attention logits
__device__ inline void gemm_epilogue(f32x4 acc[8], int row0, int w, int col, int kq,
                                     const float* __restrict__ atts,
                                     const float* __restrict__ attd,
                                     u16* __restrict__ hb,
                                     float* __restrict__ a_src,
                                     float* __restrict__ a_dst) {
    float as0[4], as1[4], ad0[4], ad1[4];
#pragma unroll
    for (int q = 0; q < 4; ++q) {
        as0[q] = atts[q * 32 + col];
        as1[q] = atts[q * 32 + 16 + col];
        ad0[q] = attd[q * 32 + col];
        ad1[q] = attd[q * 32 + 16 + col];
    }
#pragma unroll
    for (int r = 0; r < 4; ++r) {
        int node = row0 + w * 16 + kq * 4 + r;
        float ps[4], pd[4];
#pragma unroll
        for (int q = 0; q < 4; ++q) {
            float d0 = acc[2 * q][r], d1 = acc[2 * q + 1][r];
            ps[q] = d0 * as0[q] + d1 * as1[q];
            pd[q] = d0 * ad0[q] + d1 * ad1[q];
        }
#pragma unroll
        for (int off = 1; off < 16; off <<= 1) {
#pragma unroll
            for (int q = 0; q < 4; ++q) {
                ps[q] += __shfl_xor(ps[q], off);
                pd[q] += __shfl_xor(pd[q], off);
            }
        }
        if (node < NN) {
#pragma unroll
            for (int ct = 0; ct < 8; ++ct)
                hb[(size_t)node * 128 + ct * 16 + col] = (u16)bf16r(acc[ct][r]);
            if (col < 4) {
                float vs = col == 0 ? ps[0] : col == 1 ? ps[1] : col == 2 ? ps[2] : ps[3];
                float vd = col == 0 ? pd[0] : col == 1 ? pd[1] : col == 2 ? pd[2] : pd[3];
                a_src[node * 4 + col] = vs;
                a_dst[node * 4 + col] = vd;
            }
        }
    }
}

// ---------------- fused: gemm1 (every 5th block, LDS-free) | scatter --------
__global__ __launch_bounds__(256) void k_sg(
    const float* __restrict__ x,
    const bf16x8* __restrict__ wpH, const bf16x8* __restrict__ wpL,
    const float* __restrict__ atts, const float* __restrict__ attd,
    u16* __restrict__ hb, float* __restrict__ a_src, float* __restrict__ a_dst,
    const int* __restrict__ src, const int* __restrict__ dst,
    const int* __restrict__ occ, const int* __restrict__ row_ptr,
    int* __restrict__ src_sorted) {
    const int idx = blockIdx.x;
    const int g5 = idx / 5;
    const bool is_gemm = (idx % 5 == 0) && (g5 < GEMM_GRID);
    if (!is_gemm) {
        int nslots = (idx + 4) / 5;
        if (nslots > GEMM_GRID) nslots = GEMM_GRID;
        int sb = idx - nslots;
        int e = sb * 256 + threadIdx.x;
        if (e < NE) {
            int d = dst[e];
            src_sorted[row_ptr[d] + occ[e]] = src[e];
        }
        return;
    }
    const int t = threadIdx.x;
    const int row0 = g5 * 64;
    const int lane = t & 63;
    const int w = t >> 6;
    const int col = lane & 15, kq = lane >> 4;
    int node_a = row0 + w * 16 + col;
    if (node_a > NN - 1) node_a = NN - 1;
    const float* xrow = x + (size_t)node_a * 128 + kq * 8;
    float a[32];
#pragma unroll
    for (int kc = 0; kc < 4; ++kc) {
        *(float4*)&a[kc * 8 + 0] = *(const float4*)(xrow + kc * 32);
        *(float4*)&a[kc * 8 + 4] = *(const float4*)(xrow + kc * 32 + 4);
    }
    f32x4 acc[8];
#pragma unroll
    for (int ct = 0; ct < 8; ++ct) acc[ct] = (f32x4){0.f, 0.f, 0.f, 0.f};
#pragma unroll
    for (int kc = 0; kc < 4; ++kc) {
        u32 hh[4], ll[4];
        split_pack8(&a[kc * 8], hh, ll);
        bf16x8 ah = __builtin_bit_cast(bf16x8, (u32x4){hh[0], hh[1], hh[2], hh[3]});
        bf16x8 al = __builtin_bit_cast(bf16x8, (u32x4){ll[0], ll[1], ll[2], ll[3]});
#pragma unroll
        for (int ct = 0; ct < 8; ++ct) {
            bf16x8 bh = wpH[(kc * 8 + ct) * 64 + lane];
            bf16x8 bl = wpL[(kc * 8 + ct) * 64 + lane];
            acc[ct] = __builtin_amdgcn_mfma_f32_16x16x32_bf16(ah, bh, acc[ct], 0, 0, 0);
            acc[ct] = __builtin_amdgcn_mfma_f32_16x16x32_bf16(al, bh, acc[ct], 0, 0, 0);
            acc[ct] = __builtin_amdgcn_mfma_f32_16x16x32_bf16(ah, bl, acc[ct], 0, 0, 0);
        }
    }
    gemm_epilogue(acc, row0, w, col, kq, atts, attd, hb, a_src, a_dst);
}

// ---------------- GEMM layer 2: bf16 input (exact A), LDS-free --------------
__global__ __launch_bounds__(256) void k_gemm2(
    const u32* __restrict__ xb,   // [NN][64] bf16 pairs (ch 2j low, 2j+1 high)
    const bf16x8* __restrict__ wpH, const bf16x8* __restrict__ wpL,
    const float* __restrict__ atts, const float* __restrict__ attd,
    u16* __restrict__ hb, float* __restrict__ a_src, float* __restrict__ a_dst) {
    const int t = threadIdx.x;
    const int row0 = blockIdx.x * 64;
    const int lane = t & 63;
    const int w = t >> 6;
    const int col = lane & 15, kq = lane >> 4;
    int node_a = row0 + w * 16 + col;
    if (node_a > NN - 1) node_a = NN - 1;
    const u32* xrow = xb + (size_t)node_a * 64 + kq * 4;
    int4 aw[4];
#pragma unroll
    for (int kc = 0; kc < 4; ++kc) aw[kc] = *(const int4*)(xrow + kc * 16);
    f32x4 acc[8];
#pragma unroll
    for (int ct = 0; ct < 8; ++ct) acc[ct] = (f32x4){0.f, 0.f, 0.f, 0.f};
#pragma unroll
    for (int kc = 0; kc < 4; ++kc) {
        bf16x8 a = __builtin_bit_cast(bf16x8, aw[kc]);
#pragma unroll
        for (int ct = 0; ct < 8; ++ct) {
            bf16x8 bh = wpH[(kc * 8 + ct) * 64 + lane];
            bf16x8 bl = wpL[(kc * 8 + ct) * 64 + lane];
            acc[ct] = __builtin_amdgcn_mfma_f32_16x16x32_bf16(a, bh, acc[ct], 0, 0, 0);
            acc[ct] = __builtin_amdgcn_mfma_f32_16x16x32_bf16(a, bl, acc[ct], 0, 0, 0);
        }
    }
    gemm_epilogue(acc, row0, w, col, kq, atts, attd, hb, a_src, a_dst);
}

// ---------------- aggregation: batched gathers (deep MLP) -------------------
// 2 nodes per 128-thread block (one wave each). Per 16-edge chunk: issue all
// 16 hb loads into wv[16] (explicit arrays force 16-in-flight), then 16
// bpermutes, then 32 FMAs. Tail runs in groups of 4 with ex==0 masking
// (clamped indices -> valid loads, zero contribution).
__global__ __launch_bounds__(128, 4) void k_agg(
    const u32* __restrict__ hb,   // [NN][64] bf16 pairs
    const float* __restrict__ a_src, const float* __restrict__ a_dst,
    const int* __restrict__ row_ptr, const int* __restrict__ src_sorted,
    const float* __restrict__ bias,
    u32* __restrict__ x1b, float* __restrict__ outp, int layer) {
    const int lane = threadIdx.x & 63;
    const int node = blockIdx.x * 2 + (threadIdx.x >> 6);
    if (node >= NN) return;
    const int q = lane >> 4;
    const int es = lane & 15;
    const int hbase = lane & 48;
    const int e0 = row_ptr[node], e1 = row_ptr[node + 1];
    const int emax = e1 - 1;
    const float advh = a_dst[node * 4 + q];
    float den = 0.f, a0a = 0.f, a0b = 0.f, a1a = 0.f, a1b = 0.f;
    if (e1 > e0) {
        int eidx = e0 + es;
        if (eidx > emax) eidx = emax;
        int sv = src_sorted[eidx];
        float av = a_src[sv * 4 + q];
        for (int ec = e0; ec < e1; ec += 16) {
            int cnt = e1 - ec;
            cnt = cnt < 16 ? cnt : 16;
            // prefetch next chunk head (clamped)
            int eidxn = ec + 16 + es;
            if (eidxn > emax) eidxn = emax;
            int svn = src_sorted[eidxn];
            float avn = a_src[svn * 4 + q];
            // logits for this chunk (one vectorized exp; masked beyond cnt)
            float lk = av + advh;
            lk = lk > 0.f ? lk : 0.2f * lk;
            float ex = (es < cnt) ? __expf(lk - 8.f) : 0.f;
            den += ex;
            if (cnt == 16) {
                u32 wv[16];
#pragma unroll
                for (int u = 0; u < 16; ++u) {
                    int su = __builtin_amdgcn_readlane(sv, u);
                    wv[u] = hb[((size_t)su << 6) + lane];
                }
                float exu[16];
#pragma unroll
                for (int u = 0; u < 16; ++u) exu[u] = __shfl(ex, hbase | u);
#pragma unroll
                for (int u = 0; u < 16; ++u) {
                    float h0 = __uint_as_float(wv[u] << 16);
                    float h1 = __uint_as_float(wv[u] & 0xFFFF0000u);
                    if (u & 1) { a0b = fmaf(exu[u], h0, a0b); a1b = fmaf(exu[u], h1, a1b); }
                    else       { a0a = fmaf(exu[u], h0, a0a); a1a = fmaf(exu[u], h1, a1a); }
                }
            } else {
                for (int u0 = 0; u0 < cnt; u0 += 4) {
                    u32 wv[4];
                    float exu[4];
#pragma unroll
                    for (int j = 0; j < 4; ++j) {
                        int su = __builtin_amdgcn_readlane(sv, u0 + j);
                        wv[j] = hb[((size_t)su << 6) + lane];
                    }
#pragma unroll
                    for (int j = 0; j < 4; ++j) exu[j] = __shfl(ex, hbase | (u0 + j));
#pragma unroll
                    for (int j = 0; j < 4; ++j) {
                        float h0 = __uint_as_float(wv[j] << 16);
                        float h1 = __uint_as_float(wv[j] & 0xFFFF0000u);
                        if (j & 1) { a0b = fmaf(exu[j], h0, a0b); a1b = fmaf(exu[j], h1, a1b); }
                        else       { a0a = fmaf(exu[j], h0, a0a); a1a = fmaf(exu[j], h1, a1a); }
                    }
                }
            }
            sv = svn;
            av = avn;
        }
    }
    float a0 = a0a + a0b, a1 = a1a + a1b;
#pragma unroll
    for (int m = 1; m < 16; m <<= 1) den += __shfl_xor(den, m);
    float inv = den > 0.f ? 1.f / den : 0.f;
    int c0 = lane * 2;
    float r0 = fmaxf(fmaf(a0, inv, bias[c0]), 0.f);
    float r1 = fmaxf(fmaf(a1, inv, bias[c0 + 1]), 0.f);
    if (layer == 1) {
        x1b[node * 64 + lane] = bf16r(r0) | (bf16r(r1) << 16);
    } else {
        u32 w1 = x1b[node * 64 + lane];
        float4 o;
        o.x = __uint_as_float(w1 << 16);          // x1[2l]
        o.y = r0;                                  // x2[2l]
        o.z = __uint_as_float(w1 & 0xFFFF0000u);  // x1[2l+1]
        o.w = r1;                                  // x2[2l+1]
        *(float4*)(outp + (size_t)node * 256 + lane * 4) = o;
    }
}

// ---------------- launch ----------------

extern "C" void kernel_launch(void* const* d_in, const int* in_sizes, int n_in,
                              void* d_out, int out_size, void* d_ws, size_t ws_size,
                              hipStream_t stream) {
    const float* x   = (const float*)d_in[0];
    const int*   ei  = (const int*)d_in[1];
    const float* W1  = (const float*)d_in[2];
    const float* as1 = (const float*)d_in[3];
    const float* ad1 = (const float*)d_in[4];
    const float* b1  = (const float*)d_in[5];
    const float* W2  = (const float*)d_in[6];
    const float* as2 = (const float*)d_in[7];
    const float* ad2 = (const float*)d_in[8];
    const float* b2  = (const float*)d_in[9];
    float* out = (float*)d_out;
    const int* src = ei;
    const int* dst = ei + NE;

    char* w = (char*)d_ws;
    size_t off = 0;
    auto alloc = [&](size_t bytes) -> void* {
        void* p = w + off;
        off = (off + bytes + 255) & ~((size_t)255);
        return p;
    };
    u16* hb         = (u16*)alloc((size_t)NN * 128 * 2);   // h as bf16
    u32* x1b        = (u32*)alloc((size_t)NN * 64 * 4);    // x1 as bf16 pairs
    float* a_src    = (float*)alloc((size_t)NN * 4 * 4);
    float* a_dst    = (float*)alloc((size_t)NN * 4 * 4);
    int* counts     = (int*)alloc((size_t)NN * 4);
    int* row_ptr    = (int*)alloc((size_t)(NN + 1) * 4);
    int* csum       = (int*)alloc(4096);
    int* occ        = (int*)alloc((size_t)NE * 4);
    int* src_sorted = (int*)alloc((size_t)NE * 4);
    bf16x8* wpH1    = (bf16x8*)alloc(2048 * 16);
    bf16x8* wpL1    = (bf16x8*)alloc(2048 * 16);
    bf16x8* wpH2    = (bf16x8*)alloc(2048 * 16);
    bf16x8* wpL2    = (bf16x8*)alloc(2048 * 16);

    const int nch = (NN + SCAN_CH - 1) / SCAN_CH;  // 98

    (void)hipMemsetAsync(counts, 0, (size_t)NN * 4, stream);
    // wpack(W1) | wpack(W2) | hist + occurrence index
    k_wh<<<WH_GRID, 256, 0, stream>>>(W1, wpH1, wpL1, W2, wpH2, wpL2,
                                      dst, counts, occ);
    k_scan1<<<nch, 256, 0, stream>>>(counts, csum);
    k_scan2<<<1, 64, 0, stream>>>(csum, nch);
    k_scan3<<<nch, 256, 0, stream>>>(counts, csum, row_ptr);
    // gemm1 (interleaved every 5th block) | atomic-free scatter
    k_sg<<<SG_GRID, 256, 0, stream>>>(x, wpH1, wpL1, as1, ad1, hb, a_src, a_dst,
                                      src, dst, occ, row_ptr, src_sorted);

    const int agg_grid = (NN + 1) / 2;
    k_agg<<<agg_grid, 128, 0, stream>>>((const u32*)hb, a_src, a_dst, row_ptr,
                                        src_sorted, b1, x1b, out, 1);
    k_gemm2<<<(NN + 63) / 64, 256, 0, stream>>>(x1b, wpH2, wpL2, as2, ad2,
                                                hb, a_src, a_dst);
    k_agg<<<agg_grid, 128, 0, stream>>>((const u32*)hb, a_src, a_dst, row_ptr,
                                        src_sorted, b2, x1b, out, 2);
}